// Round 17
// baseline (258.804 us; speedup 1.0000x reference)
//
#include <hip/hip_runtime.h>
#include <math.h>

#define IN_CAPS 512
#define QN      512
#define IN_DIM  768
#define NCAPS   64
#define DCAPS   16
#define CD      1024   // NCAPS*DCAPS

typedef _Float16 half2_t __attribute__((ext_vector_type(2)));

#if __has_builtin(__builtin_amdgcn_rcpf)
  #define RCP(x) __builtin_amdgcn_rcpf(x)
#else
  #define RCP(x) __frcp_rn(x)
#endif

// tanh via continued-fraction Pade (|x|<=~1.05, err ~4e-6)
__device__ __forceinline__ float tanh_pade(float x){
  const float x2 = x*x;
  const float num = fmaf(x2, x2 + 105.0f, 945.0f);
  const float den = fmaf(x2, fmaf(x2, 15.0f, 420.0f), 945.0f);
  return x * num * RCP(den);
}

template<int CTRL>
__device__ __forceinline__ float dpp_add(float v){
  int r = __builtin_amdgcn_update_dpp(0, __float_as_int(v), CTRL, 0xF, 0xF, true);
  return v + __int_as_float(r);
}

// full 64-lane sum -> uniform scalar (pure DPP + readlane)
__device__ __forceinline__ float wave_sum64_all(float v){
  v = dpp_add<0xB1>(v);
  v = dpp_add<0x4E>(v);
  v = dpp_add<0x141>(v);
  v = dpp_add<0x140>(v);
  v = dpp_add<0x142>(v);
  v = dpp_add<0x143>(v);
  return __int_as_float(__builtin_amdgcn_readlane(__float_as_int(v), 63));
}

#define LD16(dst, ptr) { const float4* _p=(const float4*)(ptr); \
  float4 _a=_p[0], _b=_p[1], _c=_p[2], _d=_p[3]; \
  dst[0]=_a.x; dst[1]=_a.y; dst[2]=_a.z; dst[3]=_a.w; \
  dst[4]=_b.x; dst[5]=_b.y; dst[6]=_b.z; dst[7]=_b.w; \
  dst[8]=_c.x; dst[9]=_c.y; dst[10]=_c.z; dst[11]=_c.w; \
  dst[12]=_d.x; dst[13]=_d.y; dst[14]=_d.z; dst[15]=_d.w; }

#define ST16(ptr, src) { float4* _p=(float4*)(ptr); \
  _p[0]=make_float4(src[0],src[1],src[2],src[3]); \
  _p[1]=make_float4(src[4],src[5],src[6],src[7]); \
  _p[2]=make_float4(src[8],src[9],src[10],src[11]); \
  _p[3]=make_float4(src[12],src[13],src[14],src[15]); }

#define LDH(dst, ptrf4) { const float4* _p=(const float4*)(ptrf4); \
  float4 _a=_p[0], _b=_p[1]; \
  dst[0]=__builtin_bit_cast(half2_t,_a.x); dst[1]=__builtin_bit_cast(half2_t,_a.y); \
  dst[2]=__builtin_bit_cast(half2_t,_a.z); dst[3]=__builtin_bit_cast(half2_t,_a.w); \
  dst[4]=__builtin_bit_cast(half2_t,_b.x); dst[5]=__builtin_bit_cast(half2_t,_b.y); \
  dst[6]=__builtin_bit_cast(half2_t,_b.z); dst[7]=__builtin_bit_cast(half2_t,_b.w); }

#define CVT16(dst, h) { \
  _Pragma("unroll") for (int _j=0;_j<8;_j++){ \
    dst[2*_j]   = (float)h[_j].x; \
    dst[2*_j+1] = (float)h[_j].y; } }

#define DOT16(res, x, y) { float _e=0.f,_o=0.f; \
  _Pragma("unroll") for (int _d=0;_d<16;_d+=2){ _e = fmaf(x[_d],y[_d],_e); _o = fmaf(x[_d+1],y[_d+1],_o); } \
  res = _e+_o; }

#define ACCUM(acc, m, w) { \
  _Pragma("unroll") for (int _d=0;_d<16;_d++) acc[_d] = fmaf(w, m[_d], acc[_d]); }

#define QSTAT(qcc, s1v, qq) { \
  float qc_[16]; \
  LD16(qc_, hat + (size_t)(IN_CAPS + (qq))*CD + c*16); \
  float s_=0.f; \
  _Pragma("unroll") for (int d=0;d<16;d++) s_ += qc_[d]; \
  const float mean_ = s_*(1.0f/16.0f); \
  float n2_=0.f; \
  _Pragma("unroll") for (int d=0;d<16;d++){ qcc[d]=qc_[d]-mean_; n2_ += qcc[d]*qcc[d]; } \
  s1v = __frsqrt_rn(n2_ + 1e-12f); }

#define ROT8(dst, src) { _Pragma("unroll") for (int _j=0;_j<8;_j++) dst[_j]=src[_j]; }

// decode: wave -> (q, chunk); lane = capsule
#define WDECODE() \
  const int tid = threadIdx.x; \
  const int gw  = blockIdx.x*4 + (tid >> 6); \
  const int q   = gw >> cshift; \
  const int ch  = gw & (nch-1); \
  const int c   = tid & 63;

// ---------------- K0: partial GEMM, K split 4 ways (z) ----------------
__global__ __launch_bounds__(256) void gemm_hat(const float* __restrict__ m,
                                                const float* __restrict__ q,
                                                const float* __restrict__ Ww,
                                                float* __restrict__ hatP)
{
  __shared__ float As[16][65];
  __shared__ float Bs[16][65];
  const int tid = threadIdx.x;
  const int bm = blockIdx.y, bn = blockIdx.x, kz = blockIdx.z;
  const int tx = tid & 15, ty = tid >> 4;

  float acc[4][4];
  #pragma unroll
  for (int a=0;a<4;a++)
    #pragma unroll
    for (int b=0;b<4;b++) acc[a][b]=0.0f;

  const int r  = tid >> 2;
  const int kk = (tid & 3) << 2;
  const int row = bm*64 + r;
  const float* srcA = (row < IN_CAPS) ? (m + row*IN_DIM) : (q + (row-IN_CAPS)*IN_DIM);
  const int krow = tid >> 4;
  const int cc   = (tid & 15) << 2;

  const int kbeg = kz*(IN_DIM/4), kend = kbeg + IN_DIM/4;   // 192-wide slice
  for (int k0=kbeg; k0<kend; k0+=16){
    float4 av = *(const float4*)(srcA + k0 + kk);
    As[kk+0][r]=av.x; As[kk+1][r]=av.y; As[kk+2][r]=av.z; As[kk+3][r]=av.w;
    float4 bv = *(const float4*)(Ww + (size_t)(k0+krow)*CD + bn*64 + cc);
    Bs[krow][cc+0]=bv.x; Bs[krow][cc+1]=bv.y; Bs[krow][cc+2]=bv.z; Bs[krow][cc+3]=bv.w;
    __syncthreads();
    #pragma unroll
    for (int k=0;k<16;k++){
      float a[4], b[4];
      #pragma unroll
      for (int j=0;j<4;j++) a[j] = As[k][ty*4+j];
      #pragma unroll
      for (int j=0;j<4;j++) b[j] = Bs[k][tx*4+j];
      #pragma unroll
      for (int ii=0;ii<4;ii++)
        #pragma unroll
        for (int jj=0;jj<4;jj++) acc[ii][jj] += a[ii]*b[jj];
    }
    __syncthreads();
  }
  float* dst = hatP + (size_t)kz*1048576;
  const int col0 = bn*64 + tx*4;
  #pragma unroll
  for (int ii=0;ii<4;ii++){
    const int orow = bm*64 + ty*4 + ii;
    #pragma unroll
    for (int jj=0;jj<4;jj++) dst[(size_t)orow*CD + col0 + jj] = acc[ii][jj];
  }
}

// ---------------- K0b: sum 4 partials + bias -> hat (f32) + hatH (f16, m-rows) ----------------
__global__ __launch_bounds__(256) void finish_kernel(const float4* __restrict__ hatP4,
                                                     const float* __restrict__ Wb,
                                                     float4* __restrict__ hat4,
                                                     _Float16* __restrict__ hatH)
{
  const int t = blockIdx.x*256 + threadIdx.x;   // 0..262143
  const int row = t >> 8;
  const int c4  = t & 255;
  const size_t o = (size_t)row*256 + c4;
  float4 a = hatP4[o];
  float4 b = hatP4[o + 262144];
  float4 cx = hatP4[o + 524288];
  float4 d = hatP4[o + 786432];
  const float4 wb = *(const float4*)(Wb + c4*4);
  float4 r;
  r.x = a.x+b.x+cx.x+d.x+wb.x;
  r.y = a.y+b.y+cx.y+d.y+wb.y;
  r.z = a.z+b.z+cx.z+d.z+wb.z;
  r.w = a.w+b.w+cx.w+d.w+wb.w;
  hat4[o] = r;
  if (row < IN_CAPS){
    half2_t h0, h1;
    h0.x=(_Float16)r.x; h0.y=(_Float16)r.y;
    h1.x=(_Float16)r.z; h1.y=(_Float16)r.w;
    *(float2*)(hatH + (size_t)row*CD + c4*4) =
      make_float2(__builtin_bit_cast(float,h0), __builtin_bit_cast(float,h1));
  }
}

// ---------------- K1: stats: m-rows -> rs; q-rows -> s1g + centered f16 copy (qccH) ----------------
__global__ __launch_bounds__(256) void stats_kernel(const float* __restrict__ hat,
                                                    float2* __restrict__ rs,
                                                    float* __restrict__ s1g,
                                                    _Float16* __restrict__ qccH)
{
  const int t = blockIdx.x*256 + threadIdx.x;   // 0..65535
  const int row = t >> 6, c = t & 63;
  float v[16];
  LD16(v, hat + (size_t)row*CD + c*16);
  float s=0.f;
  #pragma unroll
  for (int d=0;d<16;d++) s += v[d];
  const float mean = s*(1.0f/16.0f);
  float n2=0.f;
  #pragma unroll
  for (int d=0;d<16;d++){ float x=v[d]-mean; n2+=x*x; }
  if (row < IN_CAPS){
    rs[t] = make_float2(__frsqrt_rn(n2 + 1e-12f), s);
  } else {
    const int qr = row - IN_CAPS;
    s1g[qr*64 + c] = __frsqrt_rn(n2 + 1e-12f);
    float tbuf[8];
    #pragma unroll
    for (int j=0;j<8;j++){
      half2_t h; h.x=(_Float16)(v[2*j]-mean); h.y=(_Float16)(v[2*j+1]-mean);
      tbuf[j] = __builtin_bit_cast(float, h);
    }
    float4* dst = (float4*)(qccH + (size_t)qr*CD + c*16);
    dst[0] = make_float4(tbuf[0],tbuf[1],tbuf[2],tbuf[3]);
    dst[1] = make_float4(tbuf[4],tbuf[5],tbuf[6],tbuf[7]);
  }
}

// ---------------- P1: pass 1, pipelined (+ n1 cache store) ----------------
template<bool CACHED>
__global__ __launch_bounds__(256) void pass1_kernel(const float4* __restrict__ hatH4,
                                                    const float4* __restrict__ qccH4,
                                                    const float* __restrict__ s1g,
                                                    const float2* __restrict__ rs_g,
                                                    float* __restrict__ part,
                                                    _Float16* __restrict__ n1h,
                                                    int ilen, int nch, int cshift)
{
  WDECODE();
  float qcc1[16];
  {
    half2_t qh[8];
    LDH(qh, qccH4 + (size_t)q*128 + c*2);
    CVT16(qcc1, qh);
  }
  const float s1 = s1g[q*64+c];

  float acc[16];
  #pragma unroll
  for (int d=0;d<16;d++) acc[d]=0.f;

  const int i0 = ch*ilen;
  const float4* mp = hatH4 + (size_t)i0*128 + c*2;
  const float2* rp = rs_g + i0*64 + c;
  size_t idc = ((size_t)q*512 + i0)*64 + c;

  half2_t hc[8];
  LDH(hc, mp);
  float rc = rp->x;

  for (int i=0;i<ilen;i++){
    half2_t hn[8];
    LDH(hn, mp+128);                 // prefetch next (one-over at end: lands in s1g region, unused)
    const float rn = rp[64].x;

    float mr[16];
    CVT16(mr, hc);
    float n1;
    DOT16(n1, mr, qcc1);
    if (CACHED) n1h[idc] = (_Float16)n1;
    const float w = 0.015625f + tanh_pade(n1*rc*s1);
    ACCUM(acc, mr, w);

    ROT8(hc, hn);
    rc = rn;
    mp += 128; rp += 64; idc += 64;
  }
  ST16(part + (((size_t)(q<<cshift) + ch)*64 + c)*16, acc);
}

// ---------------- R1 ----------------
__global__ __launch_bounds__(256) void reduce1_kernel(const float* __restrict__ hat,
                                                      const float* __restrict__ part,
                                                      float* __restrict__ v1g,
                                                      float2* __restrict__ aux1,
                                                      int nchunk)
{
  const int tid = threadIdx.x;
  const int q = blockIdx.x*4 + (tid>>6), c = tid & 63;
  float hv[16];
  #pragma unroll
  for (int d=0;d<16;d++) hv[d]=0.f;
  const float* pp = part + ((size_t)q*nchunk*64 + c)*16;
  for (int ch=0; ch<nchunk; ch++, pp += 1024){
    float t[16]; LD16(t, pp);
    #pragma unroll
    for (int d=0;d<16;d++) hv[d]+=t[d];
  }
  float n2=0.f;
  #pragma unroll
  for (int d=0;d<16;d++) n2 += hv[d]*hv[d];
  const float sc = n2 / ((1.0f+n2)*sqrtf(n2+1e-8f));
  float v1[16]; float sv=0.f;
  #pragma unroll
  for (int d=0;d<16;d++){ v1[d]=hv[d]*sc; sv+=v1[d]; }
  ST16(v1g + ((size_t)q*64 + c)*16, v1);
  float qc[16]; LD16(qc, hat + (size_t)(IN_CAPS+q)*CD + c*16);
  float s=0.f, ss=0.f;
  #pragma unroll
  for (int d=0;d<16;d++){ const float t2 = 0.5f*(qc[d]+v1[d]); s+=t2; ss+=t2*t2; }
  const float mean = s*(1.0f/16.0f);
  aux1[q*64+c] = make_float2(__frsqrt_rn(ss - 16.0f*mean*mean + 1e-12f), sv*(1.0f/16.0f));
}

// ---------------- P2: pass 2, pipelined (cached: load n1, store {l1,p2} + n2d) ----------------
template<bool CACHED>
__global__ __launch_bounds__(256) void pass2_kernel(const float4* __restrict__ hatH4,
                                                    const float* __restrict__ hat,
                                                    const float2* __restrict__ rs_g,
                                                    const float* __restrict__ s1g,
                                                    const float* __restrict__ v1g,
                                                    const float2* __restrict__ aux1,
                                                    float* __restrict__ part,
                                                    _Float16* __restrict__ n1h,
                                                    float* __restrict__ c2f,
                                                    int ilen, int nch, int cshift)
{
  WDECODE();
  float qcc1[16]; float s1;
  if (CACHED){
    s1 = s1g[q*64+c];
  } else {
    QSTAT(qcc1, s1, q);
  }
  float v1[16];
  LD16(v1, v1g + ((size_t)q*64 + c)*16);
  const float2 a1 = aux1[q*64+c];
  const float s2 = a1.x, mv1 = a1.y;

  float acc[16];
  #pragma unroll
  for (int d=0;d<16;d++) acc[d]=0.f;

  const int i0 = ch*ilen;
  const float4* mp = hatH4 + (size_t)i0*128 + c*2;
  const float2* rp = rs_g + i0*64 + c;
  size_t idc = ((size_t)q*512 + i0)*64 + c;

  half2_t hc[8];
  LDH(hc, mp);
  float2 rc = *rp;
  float n1c = 0.f;
  if (CACHED) n1c = (float)n1h[idc];

  for (int i=0;i<ilen;i++){
    half2_t hn[8];
    LDH(hn, mp+128);
    const float2 rn = rp[64];
    float n1n = 0.f;
    if (CACHED) n1n = (float)n1h[idc+64];

    float mr[16];
    CVT16(mr, hc);
    float n1;
    if (CACHED) n1 = n1c;
    else { DOT16(n1, mr, qcc1); }
    float cv;
    DOT16(cv, mr, v1);
    const float p1 = tanh_pade(n1*rc.x*s1);
    const float n2d = 0.5f*(n1 + cv - mv1*rc.y);
    const float p2 = tanh_pade(n2d*rc.x*s2);
    const float l1 = p1*cv;
    if (CACHED){
      half2_t cp; cp.x = (_Float16)l1; cp.y = (_Float16)p2;
      c2f[idc] = __builtin_bit_cast(float, cp);
      n1h[idc] = (_Float16)n2d;
    }
    const float e = __expf(l1);
    const float S = wave_sum64_all(e);
    const float w = e*RCP(S) + p2;
    ACCUM(acc, mr, w);

    ROT8(hc, hn);
    rc = rn; n1c = n1n;
    mp += 128; rp += 64; idc += 64;
  }
  ST16(part + (((size_t)(q<<cshift) + ch)*64 + c)*16, acc);
}

// ---------------- R2 ----------------
__global__ __launch_bounds__(256) void reduce2_kernel(const float* __restrict__ hat,
                                                      const float* __restrict__ part,
                                                      const float* __restrict__ v1g,
                                                      float* __restrict__ v2g,
                                                      float2* __restrict__ aux2,
                                                      int nchunk)
{
  const int tid = threadIdx.x;
  const int q = blockIdx.x*4 + (tid>>6), c = tid & 63;
  float hv[16];
  #pragma unroll
  for (int d=0;d<16;d++) hv[d]=0.f;
  const float* pp = part + ((size_t)q*nchunk*64 + c)*16;
  for (int ch=0; ch<nchunk; ch++, pp += 1024){
    float t[16]; LD16(t, pp);
    #pragma unroll
    for (int d=0;d<16;d++) hv[d]+=t[d];
  }
  float n2=0.f;
  #pragma unroll
  for (int d=0;d<16;d++) n2 += hv[d]*hv[d];
  const float sc = n2 / ((1.0f+n2)*sqrtf(n2+1e-8f));
  float v2[16]; float sv=0.f;
  #pragma unroll
  for (int d=0;d<16;d++){ v2[d]=hv[d]*sc; sv+=v2[d]; }
  ST16(v2g + ((size_t)q*64 + c)*16, v2);
  float qc[16];  LD16(qc, hat + (size_t)(IN_CAPS+q)*CD + c*16);
  float v1[16];  LD16(v1, v1g + ((size_t)q*64 + c)*16);
  float s=0.f, ss=0.f;
  #pragma unroll
  for (int d=0;d<16;d++){
    const float t3 = 0.25f*qc[d] + 0.25f*v1[d] + 0.5f*v2[d];   // q_cur3
    s+=t3; ss+=t3*t3;
  }
  const float mean = s*(1.0f/16.0f);
  aux2[q*64+c] = make_float2(__frsqrt_rn(ss - 16.0f*mean*mean + 1e-12f), sv*(1.0f/16.0f));
}

// ---------------- P3: pass 3, pipelined (cached: only the cv2 dot survives) ----------------
template<bool CACHED>
__global__ __launch_bounds__(256) void pass3_kernel(const float4* __restrict__ hatH4,
                                                    const float* __restrict__ hat,
                                                    const float2* __restrict__ rs_g,
                                                    const float* __restrict__ v1g,
                                                    const float* __restrict__ v2g,
                                                    const float2* __restrict__ aux1,
                                                    const float2* __restrict__ aux2,
                                                    float* __restrict__ part,
                                                    const _Float16* __restrict__ n1h,   // holds n2d now
                                                    const float* __restrict__ c2f,     // {l1,p2}
                                                    int ilen, int nch, int cshift)
{
  WDECODE();
  float v2[16];
  LD16(v2, v2g + ((size_t)q*64 + c)*16);
  const float2 a2 = aux2[q*64+c];
  const float s3 = a2.x, mv2 = a2.y;

  float qcc1[16]; float s1=0.f, s2=0.f, mv1=0.f;
  float v1[16];
  if (!CACHED){
    QSTAT(qcc1, s1, q);
    LD16(v1, v1g + ((size_t)q*64 + c)*16);
    const float2 a1 = aux1[q*64+c];
    s2 = a1.x; mv1 = a1.y;
  }

  float acc[16];
  #pragma unroll
  for (int d=0;d<16;d++) acc[d]=0.f;

  const int i0 = ch*ilen;
  const float4* mp = hatH4 + (size_t)i0*128 + c*2;
  const float2* rp = rs_g + i0*64 + c;
  size_t idc = ((size_t)q*512 + i0)*64 + c;

  half2_t hc[8];
  LDH(hc, mp);
  float2 rc = *rp;
  float l1c=0.f, p2c=0.f, n2c=0.f;
  if (CACHED){
    half2_t cp = __builtin_bit_cast(half2_t, c2f[idc]);
    l1c = (float)cp.x; p2c = (float)cp.y;
    n2c = (float)n1h[idc];
  }

  for (int i=0;i<ilen;i++){
    half2_t hn[8];
    LDH(hn, mp+128);
    const float2 rn = rp[64];
    float l1n=0.f, p2n=0.f, n2n=0.f;
    if (CACHED){
      half2_t cp = __builtin_bit_cast(half2_t, c2f[idc+64]);
      l1n = (float)cp.x; p2n = (float)cp.y;
      n2n = (float)n1h[idc+64];
    }

    float mr[16];
    CVT16(mr, hc);
    float cw;
    DOT16(cw, mr, v2);
    float l1, p2, n2d;
    if (CACHED){ l1 = l1c; p2 = p2c; n2d = n2c; }
    else {
      float n1, cv;
      DOT16(n1, mr, qcc1); DOT16(cv, mr, v1);
      const float p1 = tanh_pade(n1*rc.x*s1);
      n2d = 0.5f*(n1 + cv - mv1*rc.y);
      p2 = tanh_pade(n2d*rc.x*s2);
      l1 = p1*cv;
    }
    const float n3 = 0.5f*(n2d + cw - mv2*rc.y);
    const float p3 = tanh_pade(n3*rc.x*s3);
    const float e  = __expf(fmaf(p2, cw, l1));
    const float S  = wave_sum64_all(e);
    const float w  = e*RCP(S) + p3;
    ACCUM(acc, mr, w);

    ROT8(hc, hn);
    rc = rn; l1c = l1n; p2c = p2n; n2c = n2n;
    mp += 128; rp += 64; idc += 64;
  }
  ST16(part + (((size_t)(q<<cshift) + ch)*64 + c)*16, acc);
}

// ---------------- R3 ----------------
__global__ __launch_bounds__(256) void reduce3_kernel(const float* __restrict__ part,
                                                      float* __restrict__ out,
                                                      int nchunk)
{
  const int tid = threadIdx.x;
  const int q = blockIdx.x*4 + (tid>>6), c = tid & 63;
  float hv[16];
  #pragma unroll
  for (int d=0;d<16;d++) hv[d]=0.f;
  const float* pp = part + ((size_t)q*nchunk*64 + c)*16;
  for (int ch=0; ch<nchunk; ch++, pp += 1024){
    float t[16]; LD16(t, pp);
    #pragma unroll
    for (int d=0;d<16;d++) hv[d]+=t[d];
  }
  float n2=0.f;
  #pragma unroll
  for (int d=0;d<16;d++) n2 += hv[d]*hv[d];
  const float sc = n2 / ((1.0f+n2)*sqrtf(n2+1e-8f));
  float o[16];
  #pragma unroll
  for (int d=0;d<16;d++) o[d] = hv[d]*sc;
  ST16(out + (size_t)q*CD + c*16, o);
}

extern "C" void kernel_launch(void* const* d_in, const int* in_sizes, int n_in,
                              void* d_out, int out_size, void* d_ws, size_t ws_size,
                              hipStream_t stream)
{
  const float* m  = (const float*)d_in[0];
  const float* q  = (const float*)d_in[1];
  const float* Ww = (const float*)d_in[2];
  const float* Wb = (const float*)d_in[3];
  float* out = (float*)d_out;

  // Fixed buffers (bytes):
  //   hat 4,194,304 | rs 262,144 | hatH 1,048,576 | s1g 131,072 | qccH 1,048,576
  //   v1g 2,097,152 | v2g 2,097,152 | aux1 262,144 | aux2 262,144  -> base 11,403,264
  // Then: [part | hatP alias] span(>=16MB) | [cached] n1h 33,554,432 | c2f 67,108,864
  char* ws = (char*)d_ws;
  float*    hat  = (float*)   (ws + 0);
  float2*   rs   = (float2*)  (ws + 4194304);
  _Float16* hatH = (_Float16*)(ws + 4456448);
  float*    s1g  = (float*)   (ws + 5505024);
  _Float16* qccH = (_Float16*)(ws + 5636096);
  float*    v1g  = (float*)   (ws + 6684672);
  float*    v2g  = (float*)   (ws + 8781824);
  float2*   aux1 = (float2*)  (ws + 10878976);
  float2*   aux2 = (float2*)  (ws + 11141120);
  const size_t base = 11403264ull;
  const size_t CACHE_BYTES = 33554432ull + 67108864ull;   // n1h + c2f

  auto spanOf = [](int nc){ size_t s = (size_t)nc*2097152ull; return s < 16777216ull ? 16777216ull : s; };

  int nchunk = 16, cshift = 4;
  bool cached;
  {
    int nc = 16, cs = 4;
    while (nc > 1 && base + spanOf(nc) + CACHE_BYTES > ws_size){ nc >>= 1; cs--; }
    cached = (base + spanOf(nc) + CACHE_BYTES <= ws_size);
    if (cached){ nchunk = nc; cshift = cs; }
    else {
      while (nchunk > 1 && base + spanOf(nchunk) > ws_size){ nchunk >>= 1; cshift--; }
    }
  }
  const size_t span = spanOf(nchunk);
  float*    part = (float*)   (ws + base);
  float*    hatP = part;                       // alias (dead before pass1)
  _Float16* n1h  = (_Float16*)(ws + base + span);
  float*    c2f  = (float*)   (ws + base + span + 33554432ull);

  const int ilen = 512 / nchunk;
  const int pblocks = (QN*nchunk)/4;   // 4 waves/block, wave = (q, chunk)

  dim3 g0(16,16,4);
  gemm_hat<<<g0, 256, 0, stream>>>(m, q, Ww, hatP);
  finish_kernel<<<1024, 256, 0, stream>>>((const float4*)hatP, Wb, (float4*)hat, hatH);
  stats_kernel<<<256, 256, 0, stream>>>(hat, rs, s1g, qccH);
  if (cached){
    pass1_kernel<true><<<pblocks, 256, 0, stream>>>((const float4*)hatH, (const float4*)qccH, s1g, rs, part, n1h, ilen, nchunk, cshift);
    reduce1_kernel<<<128, 256, 0, stream>>>(hat, part, v1g, aux1, nchunk);
    pass2_kernel<true><<<pblocks, 256, 0, stream>>>((const float4*)hatH, hat, rs, s1g, v1g, aux1, part, n1h, c2f, ilen, nchunk, cshift);
    reduce2_kernel<<<128, 256, 0, stream>>>(hat, part, v1g, v2g, aux2, nchunk);
    pass3_kernel<true><<<pblocks, 256, 0, stream>>>((const float4*)hatH, hat, rs, v1g, v2g, aux1, aux2, part, n1h, c2f, ilen, nchunk, cshift);
    reduce3_kernel<<<128, 256, 0, stream>>>(part, out, nchunk);
  } else {
    pass1_kernel<false><<<pblocks, 256, 0, stream>>>((const float4*)hatH, (const float4*)qccH, s1g, rs, part, n1h, ilen, nchunk, cshift);
    reduce1_kernel<<<128, 256, 0, stream>>>(hat, part, v1g, aux1, nchunk);
    pass2_kernel<false><<<pblocks, 256, 0, stream>>>((const float4*)hatH, hat, rs, s1g, v1g, aux1, part, n1h, c2f, ilen, nchunk, cshift);
    reduce2_kernel<<<128, 256, 0, stream>>>(hat, part, v1g, v2g, aux2, nchunk);
    pass3_kernel<false><<<pblocks, 256, 0, stream>>>((const float4*)hatH, hat, rs, v1g, v2g, aux1, aux2, part, n1h, c2f, ilen, nchunk, cshift);
    reduce3_kernel<<<128, 256, 0, stream>>>(part, out, nchunk);
  }
}

// Round 18
// 227.367 us; speedup vs baseline: 1.1383x; 1.1383x over previous
//
#include <hip/hip_runtime.h>
#include <math.h>

#define IN_CAPS 512
#define QN      512
#define IN_DIM  768
#define NCAPS   64
#define DCAPS   16
#define CD      1024   // NCAPS*DCAPS

typedef _Float16 half2_t __attribute__((ext_vector_type(2)));

#if __has_builtin(__builtin_amdgcn_rcpf)
  #define RCP(x) __builtin_amdgcn_rcpf(x)
#else
  #define RCP(x) __frcp_rn(x)
#endif

// tanh via continued-fraction Pade (|x|<=~1.05, err ~4e-6)
__device__ __forceinline__ float tanh_pade(float x){
  const float x2 = x*x;
  const float num = fmaf(x2, x2 + 105.0f, 945.0f);
  const float den = fmaf(x2, fmaf(x2, 15.0f, 420.0f), 945.0f);
  return x * num * RCP(den);
}

template<int CTRL>
__device__ __forceinline__ float dpp_add(float v){
  int r = __builtin_amdgcn_update_dpp(0, __float_as_int(v), CTRL, 0xF, 0xF, true);
  return v + __int_as_float(r);
}

// full 64-lane sum -> uniform scalar (pure DPP + readlane)
__device__ __forceinline__ float wave_sum64_all(float v){
  v = dpp_add<0xB1>(v);
  v = dpp_add<0x4E>(v);
  v = dpp_add<0x141>(v);
  v = dpp_add<0x140>(v);
  v = dpp_add<0x142>(v);
  v = dpp_add<0x143>(v);
  return __int_as_float(__builtin_amdgcn_readlane(__float_as_int(v), 63));
}

#define LD16(dst, ptr) { const float4* _p=(const float4*)(ptr); \
  float4 _a=_p[0], _b=_p[1], _c=_p[2], _d=_p[3]; \
  dst[0]=_a.x; dst[1]=_a.y; dst[2]=_a.z; dst[3]=_a.w; \
  dst[4]=_b.x; dst[5]=_b.y; dst[6]=_b.z; dst[7]=_b.w; \
  dst[8]=_c.x; dst[9]=_c.y; dst[10]=_c.z; dst[11]=_c.w; \
  dst[12]=_d.x; dst[13]=_d.y; dst[14]=_d.z; dst[15]=_d.w; }

#define ST16(ptr, src) { float4* _p=(float4*)(ptr); \
  _p[0]=make_float4(src[0],src[1],src[2],src[3]); \
  _p[1]=make_float4(src[4],src[5],src[6],src[7]); \
  _p[2]=make_float4(src[8],src[9],src[10],src[11]); \
  _p[3]=make_float4(src[12],src[13],src[14],src[15]); }

#define LDH(dst, ptrf4) { const float4* _p=(const float4*)(ptrf4); \
  float4 _a=_p[0], _b=_p[1]; \
  dst[0]=__builtin_bit_cast(half2_t,_a.x); dst[1]=__builtin_bit_cast(half2_t,_a.y); \
  dst[2]=__builtin_bit_cast(half2_t,_a.z); dst[3]=__builtin_bit_cast(half2_t,_a.w); \
  dst[4]=__builtin_bit_cast(half2_t,_b.x); dst[5]=__builtin_bit_cast(half2_t,_b.y); \
  dst[6]=__builtin_bit_cast(half2_t,_b.z); dst[7]=__builtin_bit_cast(half2_t,_b.w); }

#define CVT16(dst, h) { \
  _Pragma("unroll") for (int _j=0;_j<8;_j++){ \
    dst[2*_j]   = (float)h[_j].x; \
    dst[2*_j+1] = (float)h[_j].y; } }

#define DOT16(res, x, y) { float _e=0.f,_o=0.f; \
  _Pragma("unroll") for (int _d=0;_d<16;_d+=2){ _e = fmaf(x[_d],y[_d],_e); _o = fmaf(x[_d+1],y[_d+1],_o); } \
  res = _e+_o; }

#define ACCUM(acc, m, w) { \
  _Pragma("unroll") for (int _d=0;_d<16;_d++) acc[_d] = fmaf(w, m[_d], acc[_d]); }

#define QSTAT(qcc, s1v, qq) { \
  float qc_[16]; \
  LD16(qc_, hat + (size_t)(IN_CAPS + (qq))*CD + c*16); \
  float s_=0.f; \
  _Pragma("unroll") for (int d=0;d<16;d++) s_ += qc_[d]; \
  const float mean_ = s_*(1.0f/16.0f); \
  float n2_=0.f; \
  _Pragma("unroll") for (int d=0;d<16;d++){ qcc[d]=qc_[d]-mean_; n2_ += qcc[d]*qcc[d]; } \
  s1v = __frsqrt_rn(n2_ + 1e-12f); }

// decode: wave -> (q, chunk); lane = capsule
#define WDECODE() \
  const int tid = threadIdx.x; \
  const int gw  = blockIdx.x*4 + (tid >> 6); \
  const int q   = gw >> cshift; \
  const int ch  = gw & (nch-1); \
  const int c   = tid & 63;

// ---------------- K0: partial GEMM, K split 4 ways (z) ----------------
__global__ __launch_bounds__(256) void gemm_hat(const float* __restrict__ m,
                                                const float* __restrict__ q,
                                                const float* __restrict__ Ww,
                                                float* __restrict__ hatP)
{
  __shared__ float As[16][65];
  __shared__ float Bs[16][65];
  const int tid = threadIdx.x;
  const int bm = blockIdx.y, bn = blockIdx.x, kz = blockIdx.z;
  const int tx = tid & 15, ty = tid >> 4;

  float acc[4][4];
  #pragma unroll
  for (int a=0;a<4;a++)
    #pragma unroll
    for (int b=0;b<4;b++) acc[a][b]=0.0f;

  const int r  = tid >> 2;
  const int kk = (tid & 3) << 2;
  const int row = bm*64 + r;
  const float* srcA = (row < IN_CAPS) ? (m + row*IN_DIM) : (q + (row-IN_CAPS)*IN_DIM);
  const int krow = tid >> 4;
  const int cc   = (tid & 15) << 2;

  const int kbeg = kz*(IN_DIM/4), kend = kbeg + IN_DIM/4;   // 192-wide slice
  for (int k0=kbeg; k0<kend; k0+=16){
    float4 av = *(const float4*)(srcA + k0 + kk);
    As[kk+0][r]=av.x; As[kk+1][r]=av.y; As[kk+2][r]=av.z; As[kk+3][r]=av.w;
    float4 bv = *(const float4*)(Ww + (size_t)(k0+krow)*CD + bn*64 + cc);
    Bs[krow][cc+0]=bv.x; Bs[krow][cc+1]=bv.y; Bs[krow][cc+2]=bv.z; Bs[krow][cc+3]=bv.w;
    __syncthreads();
    #pragma unroll
    for (int k=0;k<16;k++){
      float a[4], b[4];
      #pragma unroll
      for (int j=0;j<4;j++) a[j] = As[k][ty*4+j];
      #pragma unroll
      for (int j=0;j<4;j++) b[j] = Bs[k][tx*4+j];
      #pragma unroll
      for (int ii=0;ii<4;ii++)
        #pragma unroll
        for (int jj=0;jj<4;jj++) acc[ii][jj] += a[ii]*b[jj];
    }
    __syncthreads();
  }
  float* dst = hatP + (size_t)kz*1048576;
  const int col0 = bn*64 + tx*4;
  #pragma unroll
  for (int ii=0;ii<4;ii++){
    const int orow = bm*64 + ty*4 + ii;
    #pragma unroll
    for (int jj=0;jj<4;jj++) dst[(size_t)orow*CD + col0 + jj] = acc[ii][jj];
  }
}

// ---------------- K0b: sum 4 partials + bias -> hat (f32) + hatH (f16, m-rows) ----------------
__global__ __launch_bounds__(256) void finish_kernel(const float4* __restrict__ hatP4,
                                                     const float* __restrict__ Wb,
                                                     float4* __restrict__ hat4,
                                                     _Float16* __restrict__ hatH)
{
  const int t = blockIdx.x*256 + threadIdx.x;   // 0..262143
  const int row = t >> 8;
  const int c4  = t & 255;
  const size_t o = (size_t)row*256 + c4;
  float4 a = hatP4[o];
  float4 b = hatP4[o + 262144];
  float4 cx = hatP4[o + 524288];
  float4 d = hatP4[o + 786432];
  const float4 wb = *(const float4*)(Wb + c4*4);
  float4 r;
  r.x = a.x+b.x+cx.x+d.x+wb.x;
  r.y = a.y+b.y+cx.y+d.y+wb.y;
  r.z = a.z+b.z+cx.z+d.z+wb.z;
  r.w = a.w+b.w+cx.w+d.w+wb.w;
  hat4[o] = r;
  if (row < IN_CAPS){
    half2_t h0, h1;
    h0.x=(_Float16)r.x; h0.y=(_Float16)r.y;
    h1.x=(_Float16)r.z; h1.y=(_Float16)r.w;
    *(float2*)(hatH + (size_t)row*CD + c4*4) =
      make_float2(__builtin_bit_cast(float,h0), __builtin_bit_cast(float,h1));
  }
}

// ---------------- K1: stats: m-rows -> rs; q-rows -> s1g + centered f16 copy (qccH) ----------------
__global__ __launch_bounds__(256) void stats_kernel(const float* __restrict__ hat,
                                                    float2* __restrict__ rs,
                                                    float* __restrict__ s1g,
                                                    _Float16* __restrict__ qccH)
{
  const int t = blockIdx.x*256 + threadIdx.x;   // 0..65535
  const int row = t >> 6, c = t & 63;
  float v[16];
  LD16(v, hat + (size_t)row*CD + c*16);
  float s=0.f;
  #pragma unroll
  for (int d=0;d<16;d++) s += v[d];
  const float mean = s*(1.0f/16.0f);
  float n2=0.f;
  #pragma unroll
  for (int d=0;d<16;d++){ float x=v[d]-mean; n2+=x*x; }
  if (row < IN_CAPS){
    rs[t] = make_float2(__frsqrt_rn(n2 + 1e-12f), s);
  } else {
    const int qr = row - IN_CAPS;
    s1g[qr*64 + c] = __frsqrt_rn(n2 + 1e-12f);
    float tbuf[8];
    #pragma unroll
    for (int j=0;j<8;j++){
      half2_t h; h.x=(_Float16)(v[2*j]-mean); h.y=(_Float16)(v[2*j+1]-mean);
      tbuf[j] = __builtin_bit_cast(float, h);
    }
    float4* dst = (float4*)(qccH + (size_t)qr*CD + c*16);
    dst[0] = make_float4(tbuf[0],tbuf[1],tbuf[2],tbuf[3]);
    dst[1] = make_float4(tbuf[4],tbuf[5],tbuf[6],tbuf[7]);
  }
}

// ---------------- P1: pass 1 (+ n1 cache store), R16 loop structure ----------------
template<bool CACHED>
__global__ __launch_bounds__(256) void pass1_kernel(const float4* __restrict__ hatH4,
                                                    const float4* __restrict__ qccH4,
                                                    const float* __restrict__ s1g,
                                                    const float2* __restrict__ rs_g,
                                                    float* __restrict__ part,
                                                    _Float16* __restrict__ n1h,
                                                    int ilen, int nch, int cshift)
{
  WDECODE();
  float qcc1[16];
  {
    half2_t qh[8];
    LDH(qh, qccH4 + (size_t)q*128 + c*2);
    CVT16(qcc1, qh);
  }
  const float s1 = s1g[q*64+c];

  float acc[16];
  #pragma unroll
  for (int d=0;d<16;d++) acc[d]=0.f;

  const int i0 = ch*ilen;
  const float4* mp = hatH4 + (size_t)i0*128 + c*2;
  const float2* rp = rs_g + i0*64 + c;
  size_t idx = ((size_t)q*512 + i0)*64 + c;
  for (int i=0;i<ilen;i+=2, mp+=256, rp+=128, idx+=128){
    half2_t ha[8], hb[8];
    LDH(ha, mp); LDH(hb, mp+128);
    float ma[16], mb[16];
    CVT16(ma, ha); CVT16(mb, hb);
    const float ra = rp[0].x, rb = rp[64].x;
    float nA, nB;
    DOT16(nA, ma, qcc1);
    DOT16(nB, mb, qcc1);
    if (CACHED){
      n1h[idx]    = (_Float16)nA;
      n1h[idx+64] = (_Float16)nB;
    }
    const float wA = 0.015625f + tanh_pade(nA*ra*s1);
    const float wB = 0.015625f + tanh_pade(nB*rb*s1);
    ACCUM(acc, ma, wA);
    ACCUM(acc, mb, wB);
  }
  ST16(part + (((size_t)(q<<cshift) + ch)*64 + c)*16, acc);
}

// ---------------- R1 ----------------
__global__ __launch_bounds__(256) void reduce1_kernel(const float* __restrict__ hat,
                                                      const float* __restrict__ part,
                                                      float* __restrict__ v1g,
                                                      float2* __restrict__ aux1,
                                                      int nchunk)
{
  const int tid = threadIdx.x;
  const int q = blockIdx.x*4 + (tid>>6), c = tid & 63;
  float hv[16];
  #pragma unroll
  for (int d=0;d<16;d++) hv[d]=0.f;
  const float* pp = part + ((size_t)q*nchunk*64 + c)*16;
  for (int ch=0; ch<nchunk; ch++, pp += 1024){
    float t[16]; LD16(t, pp);
    #pragma unroll
    for (int d=0;d<16;d++) hv[d]+=t[d];
  }
  float n2=0.f;
  #pragma unroll
  for (int d=0;d<16;d++) n2 += hv[d]*hv[d];
  const float sc = n2 / ((1.0f+n2)*sqrtf(n2+1e-8f));
  float v1[16]; float sv=0.f;
  #pragma unroll
  for (int d=0;d<16;d++){ v1[d]=hv[d]*sc; sv+=v1[d]; }
  ST16(v1g + ((size_t)q*64 + c)*16, v1);
  float qc[16]; LD16(qc, hat + (size_t)(IN_CAPS+q)*CD + c*16);
  float s=0.f, ss=0.f;
  #pragma unroll
  for (int d=0;d<16;d++){ const float t2 = 0.5f*(qc[d]+v1[d]); s+=t2; ss+=t2*t2; }
  const float mean = s*(1.0f/16.0f);
  aux1[q*64+c] = make_float2(__frsqrt_rn(ss - 16.0f*mean*mean + 1e-12f), sv*(1.0f/16.0f));
}

// ---------------- P2: pass 2 (cached: load n1, store {l1,p2} + n2d), R16 structure ----------------
template<bool CACHED>
__global__ __launch_bounds__(256) void pass2_kernel(const float4* __restrict__ hatH4,
                                                    const float* __restrict__ hat,
                                                    const float2* __restrict__ rs_g,
                                                    const float* __restrict__ s1g,
                                                    const float* __restrict__ v1g,
                                                    const float2* __restrict__ aux1,
                                                    float* __restrict__ part,
                                                    _Float16* __restrict__ n1h,
                                                    float* __restrict__ c2f,
                                                    int ilen, int nch, int cshift)
{
  WDECODE();
  float qcc1[16]; float s1;
  if (CACHED){
    s1 = s1g[q*64+c];
  } else {
    QSTAT(qcc1, s1, q);
  }
  float v1[16];
  LD16(v1, v1g + ((size_t)q*64 + c)*16);
  const float2 a1 = aux1[q*64+c];
  const float s2 = a1.x, mv1 = a1.y;

  float acc[16];
  #pragma unroll
  for (int d=0;d<16;d++) acc[d]=0.f;

  const int i0 = ch*ilen;
  const float4* mp = hatH4 + (size_t)i0*128 + c*2;
  const float2* rp = rs_g + i0*64 + c;
  size_t idx = ((size_t)q*512 + i0)*64 + c;
  for (int i=0;i<ilen;i+=2, mp+=256, rp+=128, idx+=128){
    half2_t ha[8], hb[8];
    LDH(ha, mp); LDH(hb, mp+128);
    float ma[16], mb[16];
    CVT16(ma, ha); CVT16(mb, hb);
    const float2 ra = rp[0], rb = rp[64];
    float n1A, n1B, cvA, cvB;
    if (CACHED){
      n1A = (float)n1h[idx];
      n1B = (float)n1h[idx+64];
    } else {
      DOT16(n1A, ma, qcc1);
      DOT16(n1B, mb, qcc1);
    }
    DOT16(cvA, ma, v1);
    DOT16(cvB, mb, v1);
    const float p1A = tanh_pade(n1A*ra.x*s1);
    const float n2A = 0.5f*(n1A + cvA - mv1*ra.y);
    const float p2A = tanh_pade(n2A*ra.x*s2);
    const float p1B = tanh_pade(n1B*rb.x*s1);
    const float n2B = 0.5f*(n1B + cvB - mv1*rb.y);
    const float p2B = tanh_pade(n2B*rb.x*s2);
    const float l1A = p1A*cvA;
    const float l1B = p1B*cvB;
    if (CACHED){
      half2_t cA; cA.x = (_Float16)l1A; cA.y = (_Float16)p2A;
      half2_t cB; cB.x = (_Float16)l1B; cB.y = (_Float16)p2B;
      c2f[idx]    = __builtin_bit_cast(float, cA);
      c2f[idx+64] = __builtin_bit_cast(float, cB);
      n1h[idx]    = (_Float16)n2A;
      n1h[idx+64] = (_Float16)n2B;
    }
    const float eA = __expf(l1A);
    const float eB = __expf(l1B);
    const float SA = wave_sum64_all(eA);
    const float SB = wave_sum64_all(eB);
    const float wA = eA*RCP(SA) + p2A;
    const float wB = eB*RCP(SB) + p2B;
    ACCUM(acc, ma, wA);
    ACCUM(acc, mb, wB);
  }
  ST16(part + (((size_t)(q<<cshift) + ch)*64 + c)*16, acc);
}

// ---------------- R2 ----------------
__global__ __launch_bounds__(256) void reduce2_kernel(const float* __restrict__ hat,
                                                      const float* __restrict__ part,
                                                      const float* __restrict__ v1g,
                                                      float* __restrict__ v2g,
                                                      float2* __restrict__ aux2,
                                                      int nchunk)
{
  const int tid = threadIdx.x;
  const int q = blockIdx.x*4 + (tid>>6), c = tid & 63;
  float hv[16];
  #pragma unroll
  for (int d=0;d<16;d++) hv[d]=0.f;
  const float* pp = part + ((size_t)q*nchunk*64 + c)*16;
  for (int ch=0; ch<nchunk; ch++, pp += 1024){
    float t[16]; LD16(t, pp);
    #pragma unroll
    for (int d=0;d<16;d++) hv[d]+=t[d];
  }
  float n2=0.f;
  #pragma unroll
  for (int d=0;d<16;d++) n2 += hv[d]*hv[d];
  const float sc = n2 / ((1.0f+n2)*sqrtf(n2+1e-8f));
  float v2[16]; float sv=0.f;
  #pragma unroll
  for (int d=0;d<16;d++){ v2[d]=hv[d]*sc; sv+=v2[d]; }
  ST16(v2g + ((size_t)q*64 + c)*16, v2);
  float qc[16];  LD16(qc, hat + (size_t)(IN_CAPS+q)*CD + c*16);
  float v1[16];  LD16(v1, v1g + ((size_t)q*64 + c)*16);
  float s=0.f, ss=0.f;
  #pragma unroll
  for (int d=0;d<16;d++){
    const float t3 = 0.25f*qc[d] + 0.25f*v1[d] + 0.5f*v2[d];   // q_cur3
    s+=t3; ss+=t3*t3;
  }
  const float mean = s*(1.0f/16.0f);
  aux2[q*64+c] = make_float2(__frsqrt_rn(ss - 16.0f*mean*mean + 1e-12f), sv*(1.0f/16.0f));
}

// ---------------- P3: pass 3 (cached: only the cv2 dot survives), R16 structure ----------------
template<bool CACHED>
__global__ __launch_bounds__(256) void pass3_kernel(const float4* __restrict__ hatH4,
                                                    const float* __restrict__ hat,
                                                    const float2* __restrict__ rs_g,
                                                    const float* __restrict__ v1g,
                                                    const float* __restrict__ v2g,
                                                    const float2* __restrict__ aux1,
                                                    const float2* __restrict__ aux2,
                                                    float* __restrict__ part,
                                                    const _Float16* __restrict__ n1h,   // holds n2d now
                                                    const float* __restrict__ c2f,     // {l1,p2}
                                                    int ilen, int nch, int cshift)
{
  WDECODE();
  float v2[16];
  LD16(v2, v2g + ((size_t)q*64 + c)*16);
  const float2 a2 = aux2[q*64+c];
  const float s3 = a2.x, mv2 = a2.y;

  float qcc1[16]; float s1=0.f, s2=0.f, mv1=0.f;
  float v1[16];
  if (!CACHED){
    QSTAT(qcc1, s1, q);
    LD16(v1, v1g + ((size_t)q*64 + c)*16);
    const float2 a1 = aux1[q*64+c];
    s2 = a1.x; mv1 = a1.y;
  }

  float acc[16];
  #pragma unroll
  for (int d=0;d<16;d++) acc[d]=0.f;

  const int i0 = ch*ilen;
  const float4* mp = hatH4 + (size_t)i0*128 + c*2;
  const float2* rp = rs_g + i0*64 + c;
  size_t idx = ((size_t)q*512 + i0)*64 + c;
  for (int i=0;i<ilen;i+=2, mp+=256, rp+=128, idx+=128){
    half2_t ha[8], hb[8];
    LDH(ha, mp); LDH(hb, mp+128);
    float ma[16], mb[16];
    CVT16(ma, ha); CVT16(mb, hb);
    const float2 ra = rp[0], rb = rp[64];
    float cwA, cwB;
    DOT16(cwA, ma, v2);
    DOT16(cwB, mb, v2);
    float l1A, p2A, n2A, l1B, p2B, n2B;
    if (CACHED){
      half2_t cA = __builtin_bit_cast(half2_t, c2f[idx]);
      half2_t cB = __builtin_bit_cast(half2_t, c2f[idx+64]);
      l1A = (float)cA.x; p2A = (float)cA.y;
      l1B = (float)cB.x; p2B = (float)cB.y;
      n2A = (float)n1h[idx];
      n2B = (float)n1h[idx+64];
    } else {
      float n1A, cvA, n1B, cvB;
      DOT16(n1A, ma, qcc1); DOT16(cvA, ma, v1);
      DOT16(n1B, mb, qcc1); DOT16(cvB, mb, v1);
      const float p1A = tanh_pade(n1A*ra.x*s1);
      n2A = 0.5f*(n1A + cvA - mv1*ra.y);
      p2A = tanh_pade(n2A*ra.x*s2);
      l1A = p1A*cvA;
      const float p1B = tanh_pade(n1B*rb.x*s1);
      n2B = 0.5f*(n1B + cvB - mv1*rb.y);
      p2B = tanh_pade(n2B*rb.x*s2);
      l1B = p1B*cvB;
    }
    const float n3A = 0.5f*(n2A + cwA - mv2*ra.y);
    const float p3A = tanh_pade(n3A*ra.x*s3);
    const float n3B = 0.5f*(n2B + cwB - mv2*rb.y);
    const float p3B = tanh_pade(n3B*rb.x*s3);
    const float eA = __expf(fmaf(p2A, cwA, l1A));
    const float eB = __expf(fmaf(p2B, cwB, l1B));
    const float SA = wave_sum64_all(eA);
    const float SB = wave_sum64_all(eB);
    const float wA = eA*RCP(SA) + p3A;
    const float wB = eB*RCP(SB) + p3B;
    ACCUM(acc, ma, wA);
    ACCUM(acc, mb, wB);
  }
  ST16(part + (((size_t)(q<<cshift) + ch)*64 + c)*16, acc);
}

// ---------------- R3 ----------------
__global__ __launch_bounds__(256) void reduce3_kernel(const float* __restrict__ part,
                                                      float* __restrict__ out,
                                                      int nchunk)
{
  const int tid = threadIdx.x;
  const int q = blockIdx.x*4 + (tid>>6), c = tid & 63;
  float hv[16];
  #pragma unroll
  for (int d=0;d<16;d++) hv[d]=0.f;
  const float* pp = part + ((size_t)q*nchunk*64 + c)*16;
  for (int ch=0; ch<nchunk; ch++, pp += 1024){
    float t[16]; LD16(t, pp);
    #pragma unroll
    for (int d=0;d<16;d++) hv[d]+=t[d];
  }
  float n2=0.f;
  #pragma unroll
  for (int d=0;d<16;d++) n2 += hv[d]*hv[d];
  const float sc = n2 / ((1.0f+n2)*sqrtf(n2+1e-8f));
  float o[16];
  #pragma unroll
  for (int d=0;d<16;d++) o[d] = hv[d]*sc;
  ST16(out + (size_t)q*CD + c*16, o);
}

extern "C" void kernel_launch(void* const* d_in, const int* in_sizes, int n_in,
                              void* d_out, int out_size, void* d_ws, size_t ws_size,
                              hipStream_t stream)
{
  const float* m  = (const float*)d_in[0];
  const float* q  = (const float*)d_in[1];
  const float* Ww = (const float*)d_in[2];
  const float* Wb = (const float*)d_in[3];
  float* out = (float*)d_out;

  // Fixed buffers (bytes):
  //   hat 4,194,304 | rs 262,144 | hatH 1,048,576 | s1g 131,072 | qccH 1,048,576
  //   v1g 2,097,152 | v2g 2,097,152 | aux1 262,144 | aux2 262,144  -> base 11,403,264
  // Then: [part | hatP alias] span(>=16MB) | [cached] n1h 33,554,432 | c2f 67,108,864
  char* ws = (char*)d_ws;
  float*    hat  = (float*)   (ws + 0);
  float2*   rs   = (float2*)  (ws + 4194304);
  _Float16* hatH = (_Float16*)(ws + 4456448);
  float*    s1g  = (float*)   (ws + 5505024);
  _Float16* qccH = (_Float16*)(ws + 5636096);
  float*    v1g  = (float*)   (ws + 6684672);
  float*    v2g  = (float*)   (ws + 8781824);
  float2*   aux1 = (float2*)  (ws + 10878976);
  float2*   aux2 = (float2*)  (ws + 11141120);
  const size_t base = 11403264ull;
  const size_t CACHE_BYTES = 33554432ull + 67108864ull;   // n1h + c2f

  auto spanOf = [](int nc){ size_t s = (size_t)nc*2097152ull; return s < 16777216ull ? 16777216ull : s; };

  int nchunk = 16, cshift = 4;
  bool cached;
  {
    int nc = 16, cs = 4;
    while (nc > 1 && base + spanOf(nc) + CACHE_BYTES > ws_size){ nc >>= 1; cs--; }
    cached = (base + spanOf(nc) + CACHE_BYTES <= ws_size);
    if (cached){ nchunk = nc; cshift = cs; }
    else {
      while (nchunk > 1 && base + spanOf(nchunk) > ws_size){ nchunk >>= 1; cshift--; }
    }
  }
  const size_t span = spanOf(nchunk);
  float*    part = (float*)   (ws + base);
  float*    hatP = part;                       // alias (dead before pass1)
  _Float16* n1h  = (_Float16*)(ws + base + span);
  float*    c2f  = (float*)   (ws + base + span + 33554432ull);

  const int ilen = 512 / nchunk;
  const int pblocks = (QN*nchunk)/4;   // 4 waves/block, wave = (q, chunk)

  dim3 g0(16,16,4);
  gemm_hat<<<g0, 256, 0, stream>>>(m, q, Ww, hatP);
  finish_kernel<<<1024, 256, 0, stream>>>((const float4*)hatP, Wb, (float4*)hat, hatH);
  stats_kernel<<<256, 256, 0, stream>>>(hat, rs, s1g, qccH);
  if (cached){
    pass1_kernel<true><<<pblocks, 256, 0, stream>>>((const float4*)hatH, (const float4*)qccH, s1g, rs, part, n1h, ilen, nchunk, cshift);
    reduce1_kernel<<<128, 256, 0, stream>>>(hat, part, v1g, aux1, nchunk);
    pass2_kernel<true><<<pblocks, 256, 0, stream>>>((const float4*)hatH, hat, rs, s1g, v1g, aux1, part, n1h, c2f, ilen, nchunk, cshift);
    reduce2_kernel<<<128, 256, 0, stream>>>(hat, part, v1g, v2g, aux2, nchunk);
    pass3_kernel<true><<<pblocks, 256, 0, stream>>>((const float4*)hatH, hat, rs, v1g, v2g, aux1, aux2, part, n1h, c2f, ilen, nchunk, cshift);
    reduce3_kernel<<<128, 256, 0, stream>>>(part, out, nchunk);
  } else {
    pass1_kernel<false><<<pblocks, 256, 0, stream>>>((const float4*)hatH, (const float4*)qccH, s1g, rs, part, n1h, ilen, nchunk, cshift);
    reduce1_kernel<<<128, 256, 0, stream>>>(hat, part, v1g, aux1, nchunk);
    pass2_kernel<false><<<pblocks, 256, 0, stream>>>((const float4*)hatH, hat, rs, s1g, v1g, aux1, part, n1h, c2f, ilen, nchunk, cshift);
    reduce2_kernel<<<128, 256, 0, stream>>>(hat, part, v1g, v2g, aux2, nchunk);
    pass3_kernel<false><<<pblocks, 256, 0, stream>>>((const float4*)hatH, hat, rs, v1g, v2g, aux1, aux2, part, n1h, c2f, ilen, nchunk, cshift);
    reduce3_kernel<<<128, 256, 0, stream>>>(part, out, nchunk);
  }
}

// Round 19
// 196.752 us; speedup vs baseline: 1.3154x; 1.1556x over previous
//
#include <hip/hip_runtime.h>
#include <math.h>

#define IN_CAPS 512
#define QN      512
#define IN_DIM  768
#define NCAPS   64
#define DCAPS   16
#define CD      1024   // NCAPS*DCAPS

typedef _Float16 half2_t __attribute__((ext_vector_type(2)));

#if __has_builtin(__builtin_amdgcn_rcpf)
  #define RCP(x) __builtin_amdgcn_rcpf(x)
#else
  #define RCP(x) __frcp_rn(x)
#endif

// tanh via continued-fraction Pade (|x|<=~1.05, err ~4e-6)
__device__ __forceinline__ float tanh_pade(float x){
  const float x2 = x*x;
  const float num = fmaf(x2, x2 + 105.0f, 945.0f);
  const float den = fmaf(x2, fmaf(x2, 15.0f, 420.0f), 945.0f);
  return x * num * RCP(den);
}

template<int CTRL>
__device__ __forceinline__ float dpp_add(float v){
  int r = __builtin_amdgcn_update_dpp(0, __float_as_int(v), CTRL, 0xF, 0xF, true);
  return v + __int_as_float(r);
}

// full 64-lane sum -> uniform scalar (pure DPP + readlane)
__device__ __forceinline__ float wave_sum64_all(float v){
  v = dpp_add<0xB1>(v);
  v = dpp_add<0x4E>(v);
  v = dpp_add<0x141>(v);
  v = dpp_add<0x140>(v);
  v = dpp_add<0x142>(v);
  v = dpp_add<0x143>(v);
  return __int_as_float(__builtin_amdgcn_readlane(__float_as_int(v), 63));
}

#define LD16(dst, ptr) { const float4* _p=(const float4*)(ptr); \
  float4 _a=_p[0], _b=_p[1], _c=_p[2], _d=_p[3]; \
  dst[0]=_a.x; dst[1]=_a.y; dst[2]=_a.z; dst[3]=_a.w; \
  dst[4]=_b.x; dst[5]=_b.y; dst[6]=_b.z; dst[7]=_b.w; \
  dst[8]=_c.x; dst[9]=_c.y; dst[10]=_c.z; dst[11]=_c.w; \
  dst[12]=_d.x; dst[13]=_d.y; dst[14]=_d.z; dst[15]=_d.w; }

#define ST16(ptr, src) { float4* _p=(float4*)(ptr); \
  _p[0]=make_float4(src[0],src[1],src[2],src[3]); \
  _p[1]=make_float4(src[4],src[5],src[6],src[7]); \
  _p[2]=make_float4(src[8],src[9],src[10],src[11]); \
  _p[3]=make_float4(src[12],src[13],src[14],src[15]); }

#define LDH(dst, ptrf4) { const float4* _p=(const float4*)(ptrf4); \
  float4 _a=_p[0], _b=_p[1]; \
  dst[0]=__builtin_bit_cast(half2_t,_a.x); dst[1]=__builtin_bit_cast(half2_t,_a.y); \
  dst[2]=__builtin_bit_cast(half2_t,_a.z); dst[3]=__builtin_bit_cast(half2_t,_a.w); \
  dst[4]=__builtin_bit_cast(half2_t,_b.x); dst[5]=__builtin_bit_cast(half2_t,_b.y); \
  dst[6]=__builtin_bit_cast(half2_t,_b.z); dst[7]=__builtin_bit_cast(half2_t,_b.w); }

#define CVT16(dst, h) { \
  _Pragma("unroll") for (int _j=0;_j<8;_j++){ \
    dst[2*_j]   = (float)h[_j].x; \
    dst[2*_j+1] = (float)h[_j].y; } }

// store 16 f32 as 16 f16 (2 float4 = 32B)
#define STH16(ptr, src) { float _tb[8]; \
  _Pragma("unroll") for (int _j=0;_j<8;_j++){ half2_t _h; _h.x=(_Float16)src[2*_j]; _h.y=(_Float16)src[2*_j+1]; _tb[_j]=__builtin_bit_cast(float,_h);} \
  float4* _p=(float4*)(ptr); \
  _p[0]=make_float4(_tb[0],_tb[1],_tb[2],_tb[3]); \
  _p[1]=make_float4(_tb[4],_tb[5],_tb[6],_tb[7]); }

#define DOT16(res, x, y) { float _e=0.f,_o=0.f; \
  _Pragma("unroll") for (int _d=0;_d<16;_d+=2){ _e = fmaf(x[_d],y[_d],_e); _o = fmaf(x[_d+1],y[_d+1],_o); } \
  res = _e+_o; }

#define ACCUM(acc, m, w) { \
  _Pragma("unroll") for (int _d=0;_d<16;_d++) acc[_d] = fmaf(w, m[_d], acc[_d]); }

#define QSTAT(qcc, s1v, qq) { \
  float qc_[16]; \
  LD16(qc_, hat + (size_t)(IN_CAPS + (qq))*CD + c*16); \
  float s_=0.f; \
  _Pragma("unroll") for (int d=0;d<16;d++) s_ += qc_[d]; \
  const float mean_ = s_*(1.0f/16.0f); \
  float n2_=0.f; \
  _Pragma("unroll") for (int d=0;d<16;d++){ qcc[d]=qc_[d]-mean_; n2_ += qcc[d]*qcc[d]; } \
  s1v = __frsqrt_rn(n2_ + 1e-12f); }

// decode: wave -> (q, chunk); lane = capsule
#define WDECODE() \
  const int tid = threadIdx.x; \
  const int gw  = blockIdx.x*4 + (tid >> 6); \
  const int q   = gw >> cshift; \
  const int ch  = gw & (nch-1); \
  const int c   = tid & 63;

// ---------------- K0: partial GEMM, K split 4 ways (z) ----------------
__global__ __launch_bounds__(256) void gemm_hat(const float* __restrict__ m,
                                                const float* __restrict__ q,
                                                const float* __restrict__ Ww,
                                                float* __restrict__ hatP)
{
  __shared__ float As[16][65];
  __shared__ float Bs[16][65];
  const int tid = threadIdx.x;
  const int bm = blockIdx.y, bn = blockIdx.x, kz = blockIdx.z;
  const int tx = tid & 15, ty = tid >> 4;

  float acc[4][4];
  #pragma unroll
  for (int a=0;a<4;a++)
    #pragma unroll
    for (int b=0;b<4;b++) acc[a][b]=0.0f;

  const int r  = tid >> 2;
  const int kk = (tid & 3) << 2;
  const int row = bm*64 + r;
  const float* srcA = (row < IN_CAPS) ? (m + row*IN_DIM) : (q + (row-IN_CAPS)*IN_DIM);
  const int krow = tid >> 4;
  const int cc   = (tid & 15) << 2;

  const int kbeg = kz*(IN_DIM/4), kend = kbeg + IN_DIM/4;   // 192-wide slice
  for (int k0=kbeg; k0<kend; k0+=16){
    float4 av = *(const float4*)(srcA + k0 + kk);
    As[kk+0][r]=av.x; As[kk+1][r]=av.y; As[kk+2][r]=av.z; As[kk+3][r]=av.w;
    float4 bv = *(const float4*)(Ww + (size_t)(k0+krow)*CD + bn*64 + cc);
    Bs[krow][cc+0]=bv.x; Bs[krow][cc+1]=bv.y; Bs[krow][cc+2]=bv.z; Bs[krow][cc+3]=bv.w;
    __syncthreads();
    #pragma unroll
    for (int k=0;k<16;k++){
      float a[4], b[4];
      #pragma unroll
      for (int j=0;j<4;j++) a[j] = As[k][ty*4+j];
      #pragma unroll
      for (int j=0;j<4;j++) b[j] = Bs[k][tx*4+j];
      #pragma unroll
      for (int ii=0;ii<4;ii++)
        #pragma unroll
        for (int jj=0;jj<4;jj++) acc[ii][jj] += a[ii]*b[jj];
    }
    __syncthreads();
  }
  float* dst = hatP + (size_t)kz*1048576;
  const int col0 = bn*64 + tx*4;
  #pragma unroll
  for (int ii=0;ii<4;ii++){
    const int orow = bm*64 + ty*4 + ii;
    #pragma unroll
    for (int jj=0;jj<4;jj++) dst[(size_t)orow*CD + col0 + jj] = acc[ii][jj];
  }
}

// ---------------- K0b fused: sum partials + bias -> hat/hatH AND per-(row,c) stats ----------------
// one block per row; 256 threads handle 4 cols each via LDS staging
__global__ __launch_bounds__(256) void finish_stats_kernel(const float4* __restrict__ hatP4,
                                                           const float* __restrict__ Wb,
                                                           float4* __restrict__ hat4,
                                                           _Float16* __restrict__ hatH,
                                                           float2* __restrict__ rs,
                                                           float* __restrict__ s1g,
                                                           _Float16* __restrict__ qccH)
{
  __shared__ float rowbuf[1024];
  const int row = blockIdx.x;
  const int t = threadIdx.x;          // 0..255, each 4 cols
  const size_t o = (size_t)row*256 + t;
  float4 a = hatP4[o];
  float4 b = hatP4[o + 262144];
  float4 cx = hatP4[o + 524288];
  float4 d = hatP4[o + 786432];
  const float4 wb = *(const float4*)(Wb + t*4);
  float4 r;
  r.x = a.x+b.x+cx.x+d.x+wb.x;
  r.y = a.y+b.y+cx.y+d.y+wb.y;
  r.z = a.z+b.z+cx.z+d.z+wb.z;
  r.w = a.w+b.w+cx.w+d.w+wb.w;
  hat4[o] = r;
  if (row < IN_CAPS){
    half2_t h0, h1;
    h0.x=(_Float16)r.x; h0.y=(_Float16)r.y;
    h1.x=(_Float16)r.z; h1.y=(_Float16)r.w;
    *(float2*)(hatH + (size_t)row*CD + t*4) =
      make_float2(__builtin_bit_cast(float,h0), __builtin_bit_cast(float,h1));
  }
  rowbuf[t*4+0]=r.x; rowbuf[t*4+1]=r.y; rowbuf[t*4+2]=r.z; rowbuf[t*4+3]=r.w;
  __syncthreads();
  if (t < 64){
    const int c = t;
    float v[16];
    #pragma unroll
    for (int dd=0;dd<16;dd++) v[dd] = rowbuf[c*16+dd];
    float s=0.f;
    #pragma unroll
    for (int dd=0;dd<16;dd++) s += v[dd];
    const float mean = s*(1.0f/16.0f);
    float n2=0.f;
    #pragma unroll
    for (int dd=0;dd<16;dd++){ float x=v[dd]-mean; n2+=x*x; }
    if (row < IN_CAPS){
      rs[row*64+c] = make_float2(__frsqrt_rn(n2 + 1e-12f), s);
    } else {
      const int qr = row - IN_CAPS;
      s1g[qr*64 + c] = __frsqrt_rn(n2 + 1e-12f);
      float tbuf[8];
      #pragma unroll
      for (int j=0;j<8;j++){
        half2_t h; h.x=(_Float16)(v[2*j]-mean); h.y=(_Float16)(v[2*j+1]-mean);
        tbuf[j] = __builtin_bit_cast(float, h);
      }
      float4* dst = (float4*)(qccH + (size_t)qr*CD + c*16);
      dst[0] = make_float4(tbuf[0],tbuf[1],tbuf[2],tbuf[3]);
      dst[1] = make_float4(tbuf[4],tbuf[5],tbuf[6],tbuf[7]);
    }
  }
}

// ---------------- P1: pass 1 (+ n1 cache store) ----------------
template<bool CACHED>
__global__ __launch_bounds__(256) void pass1_kernel(const float4* __restrict__ hatH4,
                                                    const float4* __restrict__ qccH4,
                                                    const float* __restrict__ s1g,
                                                    const float2* __restrict__ rs_g,
                                                    _Float16* __restrict__ part,
                                                    _Float16* __restrict__ n1h,
                                                    int ilen, int nch, int cshift)
{
  WDECODE();
  float qcc1[16];
  {
    half2_t qh[8];
    LDH(qh, qccH4 + (size_t)q*128 + c*2);
    CVT16(qcc1, qh);
  }
  const float s1 = s1g[q*64+c];

  float acc[16];
  #pragma unroll
  for (int d=0;d<16;d++) acc[d]=0.f;

  const int i0 = ch*ilen;
  const float4* mp = hatH4 + (size_t)i0*128 + c*2;
  const float2* rp = rs_g + i0*64 + c;
  size_t idx = ((size_t)q*512 + i0)*64 + c;
  for (int i=0;i<ilen;i+=2, mp+=256, rp+=128, idx+=128){
    half2_t ha[8], hb[8];
    LDH(ha, mp); LDH(hb, mp+128);
    float ma[16], mb[16];
    CVT16(ma, ha); CVT16(mb, hb);
    const float ra = rp[0].x, rb = rp[64].x;
    float nA, nB;
    DOT16(nA, ma, qcc1);
    DOT16(nB, mb, qcc1);
    if (CACHED){
      n1h[idx]    = (_Float16)nA;
      n1h[idx+64] = (_Float16)nB;
    }
    const float wA = 0.015625f + tanh_pade(nA*ra*s1);
    const float wB = 0.015625f + tanh_pade(nB*rb*s1);
    ACCUM(acc, ma, wA);
    ACCUM(acc, mb, wB);
  }
  STH16(part + (((size_t)(q<<cshift) + ch)*64 + c)*16, acc);
}

// ---------------- R1 ----------------
__global__ __launch_bounds__(256) void reduce1_kernel(const float* __restrict__ hat,
                                                      const _Float16* __restrict__ part,
                                                      float* __restrict__ v1g,
                                                      float2* __restrict__ aux1,
                                                      int nchunk)
{
  const int tid = threadIdx.x;
  const int q = blockIdx.x*4 + (tid>>6), c = tid & 63;
  float hv[16];
  #pragma unroll
  for (int d=0;d<16;d++) hv[d]=0.f;
  const _Float16* pp = part + ((size_t)q*nchunk*64 + c)*16;
  for (int ch=0; ch<nchunk; ch++, pp += 1024){
    half2_t th[8]; LDH(th, pp);
    float t[16]; CVT16(t, th);
    #pragma unroll
    for (int d=0;d<16;d++) hv[d]+=t[d];
  }
  float n2=0.f;
  #pragma unroll
  for (int d=0;d<16;d++) n2 += hv[d]*hv[d];
  const float sc = n2 / ((1.0f+n2)*sqrtf(n2+1e-8f));
  float v1[16]; float sv=0.f;
  #pragma unroll
  for (int d=0;d<16;d++){ v1[d]=hv[d]*sc; sv+=v1[d]; }
  ST16(v1g + ((size_t)q*64 + c)*16, v1);
  float qc[16]; LD16(qc, hat + (size_t)(IN_CAPS+q)*CD + c*16);
  float s=0.f, ss=0.f;
  #pragma unroll
  for (int d=0;d<16;d++){ const float t2 = 0.5f*(qc[d]+v1[d]); s+=t2; ss+=t2*t2; }
  const float mean = s*(1.0f/16.0f);
  aux1[q*64+c] = make_float2(__frsqrt_rn(ss - 16.0f*mean*mean + 1e-12f), sv*(1.0f/16.0f));
}

// ---------------- P2: pass 2 (cached: load n1, store {l1,p2} + n2d) ----------------
template<bool CACHED>
__global__ __launch_bounds__(256) void pass2_kernel(const float4* __restrict__ hatH4,
                                                    const float* __restrict__ hat,
                                                    const float2* __restrict__ rs_g,
                                                    const float* __restrict__ s1g,
                                                    const float* __restrict__ v1g,
                                                    const float2* __restrict__ aux1,
                                                    _Float16* __restrict__ part,
                                                    _Float16* __restrict__ n1h,
                                                    float* __restrict__ c2f,
                                                    int ilen, int nch, int cshift)
{
  WDECODE();
  float qcc1[16]; float s1;
  if (CACHED){
    s1 = s1g[q*64+c];
  } else {
    QSTAT(qcc1, s1, q);
  }
  float v1[16];
  LD16(v1, v1g + ((size_t)q*64 + c)*16);
  const float2 a1 = aux1[q*64+c];
  const float s2 = a1.x, mv1 = a1.y;

  float acc[16];
  #pragma unroll
  for (int d=0;d<16;d++) acc[d]=0.f;

  const int i0 = ch*ilen;
  const float4* mp = hatH4 + (size_t)i0*128 + c*2;
  const float2* rp = rs_g + i0*64 + c;
  size_t idx = ((size_t)q*512 + i0)*64 + c;
  for (int i=0;i<ilen;i+=2, mp+=256, rp+=128, idx+=128){
    half2_t ha[8], hb[8];
    LDH(ha, mp); LDH(hb, mp+128);
    float ma[16], mb[16];
    CVT16(ma, ha); CVT16(mb, hb);
    const float2 ra = rp[0], rb = rp[64];
    float n1A, n1B, cvA, cvB;
    if (CACHED){
      n1A = (float)n1h[idx];
      n1B = (float)n1h[idx+64];
    } else {
      DOT16(n1A, ma, qcc1);
      DOT16(n1B, mb, qcc1);
    }
    DOT16(cvA, ma, v1);
    DOT16(cvB, mb, v1);
    const float p1A = tanh_pade(n1A*ra.x*s1);
    const float n2A = 0.5f*(n1A + cvA - mv1*ra.y);
    const float p2A = tanh_pade(n2A*ra.x*s2);
    const float p1B = tanh_pade(n1B*rb.x*s1);
    const float n2B = 0.5f*(n1B + cvB - mv1*rb.y);
    const float p2B = tanh_pade(n2B*rb.x*s2);
    const float l1A = p1A*cvA;
    const float l1B = p1B*cvB;
    if (CACHED){
      half2_t cA; cA.x = (_Float16)l1A; cA.y = (_Float16)p2A;
      half2_t cB; cB.x = (_Float16)l1B; cB.y = (_Float16)p2B;
      c2f[idx]    = __builtin_bit_cast(float, cA);
      c2f[idx+64] = __builtin_bit_cast(float, cB);
      n1h[idx]    = (_Float16)n2A;
      n1h[idx+64] = (_Float16)n2B;
    }
    const float eA = __expf(l1A);
    const float eB = __expf(l1B);
    const float SA = wave_sum64_all(eA);
    const float SB = wave_sum64_all(eB);
    const float wA = eA*RCP(SA) + p2A;
    const float wB = eB*RCP(SB) + p2B;
    ACCUM(acc, ma, wA);
    ACCUM(acc, mb, wB);
  }
  STH16(part + (((size_t)(q<<cshift) + ch)*64 + c)*16, acc);
}

// ---------------- R2 ----------------
__global__ __launch_bounds__(256) void reduce2_kernel(const float* __restrict__ hat,
                                                      const _Float16* __restrict__ part,
                                                      const float* __restrict__ v1g,
                                                      float* __restrict__ v2g,
                                                      float2* __restrict__ aux2,
                                                      int nchunk)
{
  const int tid = threadIdx.x;
  const int q = blockIdx.x*4 + (tid>>6), c = tid & 63;
  float hv[16];
  #pragma unroll
  for (int d=0;d<16;d++) hv[d]=0.f;
  const _Float16* pp = part + ((size_t)q*nchunk*64 + c)*16;
  for (int ch=0; ch<nchunk; ch++, pp += 1024){
    half2_t th[8]; LDH(th, pp);
    float t[16]; CVT16(t, th);
    #pragma unroll
    for (int d=0;d<16;d++) hv[d]+=t[d];
  }
  float n2=0.f;
  #pragma unroll
  for (int d=0;d<16;d++) n2 += hv[d]*hv[d];
  const float sc = n2 / ((1.0f+n2)*sqrtf(n2+1e-8f));
  float v2[16]; float sv=0.f;
  #pragma unroll
  for (int d=0;d<16;d++){ v2[d]=hv[d]*sc; sv+=v2[d]; }
  ST16(v2g + ((size_t)q*64 + c)*16, v2);
  float qc[16];  LD16(qc, hat + (size_t)(IN_CAPS+q)*CD + c*16);
  float v1[16];  LD16(v1, v1g + ((size_t)q*64 + c)*16);
  float s=0.f, ss=0.f;
  #pragma unroll
  for (int d=0;d<16;d++){
    const float t3 = 0.25f*qc[d] + 0.25f*v1[d] + 0.5f*v2[d];   // q_cur3
    s+=t3; ss+=t3*t3;
  }
  const float mean = s*(1.0f/16.0f);
  aux2[q*64+c] = make_float2(__frsqrt_rn(ss - 16.0f*mean*mean + 1e-12f), sv*(1.0f/16.0f));
}

// ---------------- P3: pass 3 (cached: only the cv2 dot survives) ----------------
template<bool CACHED>
__global__ __launch_bounds__(256) void pass3_kernel(const float4* __restrict__ hatH4,
                                                    const float* __restrict__ hat,
                                                    const float2* __restrict__ rs_g,
                                                    const float* __restrict__ v1g,
                                                    const float* __restrict__ v2g,
                                                    const float2* __restrict__ aux1,
                                                    const float2* __restrict__ aux2,
                                                    _Float16* __restrict__ part,
                                                    const _Float16* __restrict__ n1h,   // holds n2d now
                                                    const float* __restrict__ c2f,     // {l1,p2}
                                                    int ilen, int nch, int cshift)
{
  WDECODE();
  float v2[16];
  LD16(v2, v2g + ((size_t)q*64 + c)*16);
  const float2 a2 = aux2[q*64+c];
  const float s3 = a2.x, mv2 = a2.y;

  float qcc1[16]; float s1=0.f, s2=0.f, mv1=0.f;
  float v1[16];
  if (!CACHED){
    QSTAT(qcc1, s1, q);
    LD16(v1, v1g + ((size_t)q*64 + c)*16);
    const float2 a1 = aux1[q*64+c];
    s2 = a1.x; mv1 = a1.y;
  }

  float acc[16];
  #pragma unroll
  for (int d=0;d<16;d++) acc[d]=0.f;

  const int i0 = ch*ilen;
  const float4* mp = hatH4 + (size_t)i0*128 + c*2;
  const float2* rp = rs_g + i0*64 + c;
  size_t idx = ((size_t)q*512 + i0)*64 + c;
  for (int i=0;i<ilen;i+=2, mp+=256, rp+=128, idx+=128){
    half2_t ha[8], hb[8];
    LDH(ha, mp); LDH(hb, mp+128);
    float ma[16], mb[16];
    CVT16(ma, ha); CVT16(mb, hb);
    const float2 ra = rp[0], rb = rp[64];
    float cwA, cwB;
    DOT16(cwA, ma, v2);
    DOT16(cwB, mb, v2);
    float l1A, p2A, n2A, l1B, p2B, n2B;
    if (CACHED){
      half2_t cA = __builtin_bit_cast(half2_t, c2f[idx]);
      half2_t cB = __builtin_bit_cast(half2_t, c2f[idx+64]);
      l1A = (float)cA.x; p2A = (float)cA.y;
      l1B = (float)cB.x; p2B = (float)cB.y;
      n2A = (float)n1h[idx];
      n2B = (float)n1h[idx+64];
    } else {
      float n1A, cvA, n1B, cvB;
      DOT16(n1A, ma, qcc1); DOT16(cvA, ma, v1);
      DOT16(n1B, mb, qcc1); DOT16(cvB, mb, v1);
      const float p1A = tanh_pade(n1A*ra.x*s1);
      n2A = 0.5f*(n1A + cvA - mv1*ra.y);
      p2A = tanh_pade(n2A*ra.x*s2);
      l1A = p1A*cvA;
      const float p1B = tanh_pade(n1B*rb.x*s1);
      n2B = 0.5f*(n1B + cvB - mv1*rb.y);
      p2B = tanh_pade(n2B*rb.x*s2);
      l1B = p1B*cvB;
    }
    const float n3A = 0.5f*(n2A + cwA - mv2*ra.y);
    const float p3A = tanh_pade(n3A*ra.x*s3);
    const float n3B = 0.5f*(n2B + cwB - mv2*rb.y);
    const float p3B = tanh_pade(n3B*rb.x*s3);
    const float eA = __expf(fmaf(p2A, cwA, l1A));
    const float eB = __expf(fmaf(p2B, cwB, l1B));
    const float SA = wave_sum64_all(eA);
    const float SB = wave_sum64_all(eB);
    const float wA = eA*RCP(SA) + p3A;
    const float wB = eB*RCP(SB) + p3B;
    ACCUM(acc, ma, wA);
    ACCUM(acc, mb, wB);
  }
  STH16(part + (((size_t)(q<<cshift) + ch)*64 + c)*16, acc);
}

// ---------------- R3 ----------------
__global__ __launch_bounds__(256) void reduce3_kernel(const _Float16* __restrict__ part,
                                                      float* __restrict__ out,
                                                      int nchunk)
{
  const int tid = threadIdx.x;
  const int q = blockIdx.x*4 + (tid>>6), c = tid & 63;
  float hv[16];
  #pragma unroll
  for (int d=0;d<16;d++) hv[d]=0.f;
  const _Float16* pp = part + ((size_t)q*nchunk*64 + c)*16;
  for (int ch=0; ch<nchunk; ch++, pp += 1024){
    half2_t th[8]; LDH(th, pp);
    float t[16]; CVT16(t, th);
    #pragma unroll
    for (int d=0;d<16;d++) hv[d]+=t[d];
  }
  float n2=0.f;
  #pragma unroll
  for (int d=0;d<16;d++) n2 += hv[d]*hv[d];
  const float sc = n2 / ((1.0f+n2)*sqrtf(n2+1e-8f));
  float o[16];
  #pragma unroll
  for (int d=0;d<16;d++) o[d] = hv[d]*sc;
  ST16(out + (size_t)q*CD + c*16, o);
}

extern "C" void kernel_launch(void* const* d_in, const int* in_sizes, int n_in,
                              void* d_out, int out_size, void* d_ws, size_t ws_size,
                              hipStream_t stream)
{
  const float* m  = (const float*)d_in[0];
  const float* q  = (const float*)d_in[1];
  const float* Ww = (const float*)d_in[2];
  const float* Wb = (const float*)d_in[3];
  float* out = (float*)d_out;

  // Fixed buffers (bytes):
  //   hat 4,194,304 | rs 262,144 | hatH 1,048,576 | s1g 131,072 | qccH 1,048,576
  //   v1g 2,097,152 | v2g 2,097,152 | aux1 262,144 | aux2 262,144  -> base 11,403,264
  // Then: [part(f16) | hatP(f32) alias] span(>=16MB) | [cached] n1h 33,554,432 | c2f 67,108,864
  char* ws = (char*)d_ws;
  float*    hat  = (float*)   (ws + 0);
  float2*   rs   = (float2*)  (ws + 4194304);
  _Float16* hatH = (_Float16*)(ws + 4456448);
  float*    s1g  = (float*)   (ws + 5505024);
  _Float16* qccH = (_Float16*)(ws + 5636096);
  float*    v1g  = (float*)   (ws + 6684672);
  float*    v2g  = (float*)   (ws + 8781824);
  float2*   aux1 = (float2*)  (ws + 10878976);
  float2*   aux2 = (float2*)  (ws + 11141120);
  const size_t base = 11403264ull;
  const size_t CACHE_BYTES = 33554432ull + 67108864ull;   // n1h + c2f

  // part(f16) bytes = nc * 1,048,576 ; hatP(f32) needs 16,777,216 — span = max
  auto spanOf = [](int nc){ size_t s = (size_t)nc*1048576ull; return s < 16777216ull ? 16777216ull : s; };

  int nchunk = 16, cshift = 4;
  bool cached;
  {
    int nc = 16, cs = 4;
    while (nc > 1 && base + spanOf(nc) + CACHE_BYTES > ws_size){ nc >>= 1; cs--; }
    cached = (base + spanOf(nc) + CACHE_BYTES <= ws_size);
    if (cached){ nchunk = nc; cshift = cs; }
    else {
      while (nchunk > 1 && base + spanOf(nchunk) > ws_size){ nchunk >>= 1; cshift--; }
    }
  }
  const size_t span = spanOf(nchunk);
  _Float16* part = (_Float16*)(ws + base);
  float*    hatP = (float*)   (ws + base);     // alias (dead before pass1)
  _Float16* n1h  = (_Float16*)(ws + base + span);
  float*    c2f  = (float*)   (ws + base + span + 33554432ull);

  const int ilen = 512 / nchunk;
  const int pblocks = (QN*nchunk)/4;   // 4 waves/block, wave = (q, chunk)

  dim3 g0(16,16,4);
  gemm_hat<<<g0, 256, 0, stream>>>(m, q, Ww, hatP);
  finish_stats_kernel<<<1024, 256, 0, stream>>>((const float4*)hatP, Wb, (float4*)hat, hatH, rs, s1g, qccH);
  if (cached){
    pass1_kernel<true><<<pblocks, 256, 0, stream>>>((const float4*)hatH, (const float4*)qccH, s1g, rs, part, n1h, ilen, nchunk, cshift);
    reduce1_kernel<<<128, 256, 0, stream>>>(hat, part, v1g, aux1, nchunk);
    pass2_kernel<true><<<pblocks, 256, 0, stream>>>((const float4*)hatH, hat, rs, s1g, v1g, aux1, part, n1h, c2f, ilen, nchunk, cshift);
    reduce2_kernel<<<128, 256, 0, stream>>>(hat, part, v1g, v2g, aux2, nchunk);
    pass3_kernel<true><<<pblocks, 256, 0, stream>>>((const float4*)hatH, hat, rs, v1g, v2g, aux1, aux2, part, n1h, c2f, ilen, nchunk, cshift);
    reduce3_kernel<<<128, 256, 0, stream>>>(part, out, nchunk);
  } else {
    pass1_kernel<false><<<pblocks, 256, 0, stream>>>((const float4*)hatH, (const float4*)qccH, s1g, rs, part, n1h, ilen, nchunk, cshift);
    reduce1_kernel<<<128, 256, 0, stream>>>(hat, part, v1g, aux1, nchunk);
    pass2_kernel<false><<<pblocks, 256, 0, stream>>>((const float4*)hatH, hat, rs, s1g, v1g, aux1, part, n1h, c2f, ilen, nchunk, cshift);
    reduce2_kernel<<<128, 256, 0, stream>>>(hat, part, v1g, v2g, aux2, nchunk);
    pass3_kernel<false><<<pblocks, 256, 0, stream>>>((const float4*)hatH, hat, rs, v1g, v2g, aux1, aux2, part, n1h, c2f, ilen, nchunk, cshift);
    reduce3_kernel<<<128, 256, 0, stream>>>(part, out, nchunk);
  }
}

// Round 20
// 183.850 us; speedup vs baseline: 1.4077x; 1.0702x over previous
//
#include <hip/hip_runtime.h>
#include <math.h>

#define IN_CAPS 512
#define QN      512
#define IN_DIM  768
#define NCAPS   64
#define DCAPS   16
#define CD      1024   // NCAPS*DCAPS

typedef _Float16 half2_t __attribute__((ext_vector_type(2)));

#if __has_builtin(__builtin_amdgcn_rcpf)
  #define RCP(x) __builtin_amdgcn_rcpf(x)
#else
  #define RCP(x) __frcp_rn(x)
#endif

// tanh via continued-fraction Pade (|x|<=~1.05, err ~4e-6)
__device__ __forceinline__ float tanh_pade(float x){
  const float x2 = x*x;
  const float num = fmaf(x2, x2 + 105.0f, 945.0f);
  const float den = fmaf(x2, fmaf(x2, 15.0f, 420.0f), 945.0f);
  return x * num * RCP(den);
}

template<int CTRL>
__device__ __forceinline__ float dpp_add(float v){
  int r = __builtin_amdgcn_update_dpp(0, __float_as_int(v), CTRL, 0xF, 0xF, true);
  return v + __int_as_float(r);
}

// full 64-lane sum -> uniform scalar (pure DPP + readlane)
__device__ __forceinline__ float wave_sum64_all(float v){
  v = dpp_add<0xB1>(v);
  v = dpp_add<0x4E>(v);
  v = dpp_add<0x141>(v);
  v = dpp_add<0x140>(v);
  v = dpp_add<0x142>(v);
  v = dpp_add<0x143>(v);
  return __int_as_float(__builtin_amdgcn_readlane(__float_as_int(v), 63));
}

#define LD16(dst, ptr) { const float4* _p=(const float4*)(ptr); \
  float4 _a=_p[0], _b=_p[1], _c=_p[2], _d=_p[3]; \
  dst[0]=_a.x; dst[1]=_a.y; dst[2]=_a.z; dst[3]=_a.w; \
  dst[4]=_b.x; dst[5]=_b.y; dst[6]=_b.z; dst[7]=_b.w; \
  dst[8]=_c.x; dst[9]=_c.y; dst[10]=_c.z; dst[11]=_c.w; \
  dst[12]=_d.x; dst[13]=_d.y; dst[14]=_d.z; dst[15]=_d.w; }

#define ST16(ptr, src) { float4* _p=(float4*)(ptr); \
  _p[0]=make_float4(src[0],src[1],src[2],src[3]); \
  _p[1]=make_float4(src[4],src[5],src[6],src[7]); \
  _p[2]=make_float4(src[8],src[9],src[10],src[11]); \
  _p[3]=make_float4(src[12],src[13],src[14],src[15]); }

#define LDH(dst, ptrf4) { const float4* _p=(const float4*)(ptrf4); \
  float4 _a=_p[0], _b=_p[1]; \
  dst[0]=__builtin_bit_cast(half2_t,_a.x); dst[1]=__builtin_bit_cast(half2_t,_a.y); \
  dst[2]=__builtin_bit_cast(half2_t,_a.z); dst[3]=__builtin_bit_cast(half2_t,_a.w); \
  dst[4]=__builtin_bit_cast(half2_t,_b.x); dst[5]=__builtin_bit_cast(half2_t,_b.y); \
  dst[6]=__builtin_bit_cast(half2_t,_b.z); dst[7]=__builtin_bit_cast(half2_t,_b.w); }

#define CVT16(dst, h) { \
  _Pragma("unroll") for (int _j=0;_j<8;_j++){ \
    dst[2*_j]   = (float)h[_j].x; \
    dst[2*_j+1] = (float)h[_j].y; } }

// store 16 f32 as 16 f16 (2 float4 = 32B)
#define STH16(ptr, src) { float _tb[8]; \
  _Pragma("unroll") for (int _j=0;_j<8;_j++){ half2_t _h; _h.x=(_Float16)src[2*_j]; _h.y=(_Float16)src[2*_j+1]; _tb[_j]=__builtin_bit_cast(float,_h);} \
  float4* _p=(float4*)(ptr); \
  _p[0]=make_float4(_tb[0],_tb[1],_tb[2],_tb[3]); \
  _p[1]=make_float4(_tb[4],_tb[5],_tb[6],_tb[7]); }

#define DOT16(res, x, y) { float _e=0.f,_o=0.f; \
  _Pragma("unroll") for (int _d=0;_d<16;_d+=2){ _e = fmaf(x[_d],y[_d],_e); _o = fmaf(x[_d+1],y[_d+1],_o); } \
  res = _e+_o; }

#define ACCUM(acc, m, w) { \
  _Pragma("unroll") for (int _d=0;_d<16;_d++) acc[_d] = fmaf(w, m[_d], acc[_d]); }

#define QSTAT(qcc, s1v, qq) { \
  float qc_[16]; \
  LD16(qc_, hat + (size_t)(IN_CAPS + (qq))*CD + c*16); \
  float s_=0.f; \
  _Pragma("unroll") for (int d=0;d<16;d++) s_ += qc_[d]; \
  const float mean_ = s_*(1.0f/16.0f); \
  float n2_=0.f; \
  _Pragma("unroll") for (int d=0;d<16;d++){ qcc[d]=qc_[d]-mean_; n2_ += qcc[d]*qcc[d]; } \
  s1v = __frsqrt_rn(n2_ + 1e-12f); }

// decode: wave -> (q, chunk); lane = capsule
#define WDECODE() \
  const int tid = threadIdx.x; \
  const int gw  = blockIdx.x*4 + (tid >> 6); \
  const int q   = gw >> cshift; \
  const int ch  = gw & (nch-1); \
  const int c   = tid & 63;

// decode: wave -> (q-pair, chunk)
#define WDECODE2() \
  const int tid = threadIdx.x; \
  const int gw  = blockIdx.x*4 + (tid >> 6); \
  const int qp  = gw >> cshift; \
  const int ch  = gw & (nch-1); \
  const int q0  = qp*2, q1 = q0+1; \
  const int c   = tid & 63;

// ---------------- K0: partial GEMM, K split 4 ways (z) ----------------
__global__ __launch_bounds__(256) void gemm_hat(const float* __restrict__ m,
                                                const float* __restrict__ q,
                                                const float* __restrict__ Ww,
                                                float* __restrict__ hatP)
{
  __shared__ float As[16][65];
  __shared__ float Bs[16][65];
  const int tid = threadIdx.x;
  const int bm = blockIdx.y, bn = blockIdx.x, kz = blockIdx.z;
  const int tx = tid & 15, ty = tid >> 4;

  float acc[4][4];
  #pragma unroll
  for (int a=0;a<4;a++)
    #pragma unroll
    for (int b=0;b<4;b++) acc[a][b]=0.0f;

  const int r  = tid >> 2;
  const int kk = (tid & 3) << 2;
  const int row = bm*64 + r;
  const float* srcA = (row < IN_CAPS) ? (m + row*IN_DIM) : (q + (row-IN_CAPS)*IN_DIM);
  const int krow = tid >> 4;
  const int cc   = (tid & 15) << 2;

  const int kbeg = kz*(IN_DIM/4), kend = kbeg + IN_DIM/4;   // 192-wide slice
  for (int k0=kbeg; k0<kend; k0+=16){
    float4 av = *(const float4*)(srcA + k0 + kk);
    As[kk+0][r]=av.x; As[kk+1][r]=av.y; As[kk+2][r]=av.z; As[kk+3][r]=av.w;
    float4 bv = *(const float4*)(Ww + (size_t)(k0+krow)*CD + bn*64 + cc);
    Bs[krow][cc+0]=bv.x; Bs[krow][cc+1]=bv.y; Bs[krow][cc+2]=bv.z; Bs[krow][cc+3]=bv.w;
    __syncthreads();
    #pragma unroll
    for (int k=0;k<16;k++){
      float a[4], b[4];
      #pragma unroll
      for (int j=0;j<4;j++) a[j] = As[k][ty*4+j];
      #pragma unroll
      for (int j=0;j<4;j++) b[j] = Bs[k][tx*4+j];
      #pragma unroll
      for (int ii=0;ii<4;ii++)
        #pragma unroll
        for (int jj=0;jj<4;jj++) acc[ii][jj] += a[ii]*b[jj];
    }
    __syncthreads();
  }
  float* dst = hatP + (size_t)kz*1048576;
  const int col0 = bn*64 + tx*4;
  #pragma unroll
  for (int ii=0;ii<4;ii++){
    const int orow = bm*64 + ty*4 + ii;
    #pragma unroll
    for (int jj=0;jj<4;jj++) dst[(size_t)orow*CD + col0 + jj] = acc[ii][jj];
  }
}

// ---------------- K0b fused: sum partials + bias -> hat/hatH AND per-(row,c) stats ----------------
__global__ __launch_bounds__(256) void finish_stats_kernel(const float4* __restrict__ hatP4,
                                                           const float* __restrict__ Wb,
                                                           float4* __restrict__ hat4,
                                                           _Float16* __restrict__ hatH,
                                                           float2* __restrict__ rs,
                                                           float* __restrict__ s1g,
                                                           _Float16* __restrict__ qccH)
{
  __shared__ float rowbuf[1024];
  const int row = blockIdx.x;
  const int t = threadIdx.x;          // 0..255, each 4 cols
  const size_t o = (size_t)row*256 + t;
  float4 a = hatP4[o];
  float4 b = hatP4[o + 262144];
  float4 cx = hatP4[o + 524288];
  float4 d = hatP4[o + 786432];
  const float4 wb = *(const float4*)(Wb + t*4);
  float4 r;
  r.x = a.x+b.x+cx.x+d.x+wb.x;
  r.y = a.y+b.y+cx.y+d.y+wb.y;
  r.z = a.z+b.z+cx.z+d.z+wb.z;
  r.w = a.w+b.w+cx.w+d.w+wb.w;
  hat4[o] = r;
  if (row < IN_CAPS){
    half2_t h0, h1;
    h0.x=(_Float16)r.x; h0.y=(_Float16)r.y;
    h1.x=(_Float16)r.z; h1.y=(_Float16)r.w;
    *(float2*)(hatH + (size_t)row*CD + t*4) =
      make_float2(__builtin_bit_cast(float,h0), __builtin_bit_cast(float,h1));
  }
  rowbuf[t*4+0]=r.x; rowbuf[t*4+1]=r.y; rowbuf[t*4+2]=r.z; rowbuf[t*4+3]=r.w;
  __syncthreads();
  if (t < 64){
    const int c = t;
    float v[16];
    #pragma unroll
    for (int dd=0;dd<16;dd++) v[dd] = rowbuf[c*16+dd];
    float s=0.f;
    #pragma unroll
    for (int dd=0;dd<16;dd++) s += v[dd];
    const float mean = s*(1.0f/16.0f);
    float n2=0.f;
    #pragma unroll
    for (int dd=0;dd<16;dd++){ float x=v[dd]-mean; n2+=x*x; }
    if (row < IN_CAPS){
      rs[row*64+c] = make_float2(__frsqrt_rn(n2 + 1e-12f), s);
    } else {
      const int qr = row - IN_CAPS;
      s1g[qr*64 + c] = __frsqrt_rn(n2 + 1e-12f);
      float tbuf[8];
      #pragma unroll
      for (int j=0;j<8;j++){
        half2_t h; h.x=(_Float16)(v[2*j]-mean); h.y=(_Float16)(v[2*j+1]-mean);
        tbuf[j] = __builtin_bit_cast(float, h);
      }
      float4* dst = (float4*)(qccH + (size_t)qr*CD + c*16);
      dst[0] = make_float4(tbuf[0],tbuf[1],tbuf[2],tbuf[3]);
      dst[1] = make_float4(tbuf[4],tbuf[5],tbuf[6],tbuf[7]);
    }
  }
}

// ================= cached-path 2q-per-wave pass kernels =================

// ---------------- P1q2 ----------------
__global__ __launch_bounds__(256) void pass1_q2(const float4* __restrict__ hatH4,
                                                const float4* __restrict__ qccH4,
                                                const float* __restrict__ s1g,
                                                const float2* __restrict__ rs_g,
                                                _Float16* __restrict__ part,
                                                _Float16* __restrict__ n1h,
                                                int ilen, int nch, int cshift)
{
  WDECODE2();
  float qccA[16], qccB[16];
  { half2_t qh[8]; LDH(qh, qccH4 + (size_t)q0*128 + c*2); CVT16(qccA, qh); }
  { half2_t qh[8]; LDH(qh, qccH4 + (size_t)q1*128 + c*2); CVT16(qccB, qh); }
  const float s1A = s1g[q0*64+c], s1B = s1g[q1*64+c];

  float accA[16], accB[16];
  #pragma unroll
  for (int d=0;d<16;d++){ accA[d]=0.f; accB[d]=0.f; }

  const int i0 = ch*ilen;
  const float4* mp = hatH4 + (size_t)i0*128 + c*2;
  const float2* rp = rs_g + i0*64 + c;
  size_t idxA = ((size_t)q0*512 + i0)*64 + c;
  size_t idxB = idxA + 32768;   // q-stride = 512*64
  for (int i=0;i<ilen;i++, mp+=128, rp+=64, idxA+=64, idxB+=64){
    half2_t h[8];
    LDH(h, mp);
    float mr[16];
    CVT16(mr, h);
    const float rn = rp->x;
    float nA, nB;
    DOT16(nA, mr, qccA);
    DOT16(nB, mr, qccB);
    n1h[idxA] = (_Float16)nA;
    n1h[idxB] = (_Float16)nB;
    const float wA = 0.015625f + tanh_pade(nA*rn*s1A);
    const float wB = 0.015625f + tanh_pade(nB*rn*s1B);
    ACCUM(accA, mr, wA);
    ACCUM(accB, mr, wB);
  }
  STH16(part + (((size_t)(q0<<cshift) + ch)*64 + c)*16, accA);
  STH16(part + (((size_t)(q1<<cshift) + ch)*64 + c)*16, accB);
}

// ---------------- P2q2 ----------------
__global__ __launch_bounds__(256) void pass2_q2(const float4* __restrict__ hatH4,
                                                const float2* __restrict__ rs_g,
                                                const float* __restrict__ s1g,
                                                const float* __restrict__ v1g,
                                                const float2* __restrict__ aux1,
                                                _Float16* __restrict__ part,
                                                _Float16* __restrict__ n1h,
                                                float* __restrict__ c2f,
                                                int ilen, int nch, int cshift)
{
  WDECODE2();
  const float s1A = s1g[q0*64+c], s1B = s1g[q1*64+c];
  float v1A[16], v1B[16];
  LD16(v1A, v1g + ((size_t)q0*64 + c)*16);
  LD16(v1B, v1g + ((size_t)q1*64 + c)*16);
  const float2 a1A = aux1[q0*64+c];
  const float2 a1B = aux1[q1*64+c];
  const float s2A = a1A.x, mv1A = a1A.y;
  const float s2B = a1B.x, mv1B = a1B.y;

  float accA[16], accB[16];
  #pragma unroll
  for (int d=0;d<16;d++){ accA[d]=0.f; accB[d]=0.f; }

  const int i0 = ch*ilen;
  const float4* mp = hatH4 + (size_t)i0*128 + c*2;
  const float2* rp = rs_g + i0*64 + c;
  size_t idxA = ((size_t)q0*512 + i0)*64 + c;
  size_t idxB = idxA + 32768;
  for (int i=0;i<ilen;i++, mp+=128, rp+=64, idxA+=64, idxB+=64){
    half2_t h[8];
    LDH(h, mp);
    float mr[16];
    CVT16(mr, h);
    const float2 rn = *rp;
    const float n1A = (float)n1h[idxA];
    const float n1B = (float)n1h[idxB];
    float cvA, cvB;
    DOT16(cvA, mr, v1A);
    DOT16(cvB, mr, v1B);
    const float p1A = tanh_pade(n1A*rn.x*s1A);
    const float n2A = 0.5f*(n1A + cvA - mv1A*rn.y);
    const float p2A = tanh_pade(n2A*rn.x*s2A);
    const float p1B = tanh_pade(n1B*rn.x*s1B);
    const float n2B = 0.5f*(n1B + cvB - mv1B*rn.y);
    const float p2B = tanh_pade(n2B*rn.x*s2B);
    const float l1A = p1A*cvA;
    const float l1B = p1B*cvB;
    half2_t cA; cA.x = (_Float16)l1A; cA.y = (_Float16)p2A;
    half2_t cB; cB.x = (_Float16)l1B; cB.y = (_Float16)p2B;
    c2f[idxA] = __builtin_bit_cast(float, cA);
    c2f[idxB] = __builtin_bit_cast(float, cB);
    n1h[idxA] = (_Float16)n2A;
    n1h[idxB] = (_Float16)n2B;
    const float eA = __expf(l1A);
    const float eB = __expf(l1B);
    const float SA = wave_sum64_all(eA);
    const float SB = wave_sum64_all(eB);
    const float wA = eA*RCP(SA) + p2A;
    const float wB = eB*RCP(SB) + p2B;
    ACCUM(accA, mr, wA);
    ACCUM(accB, mr, wB);
  }
  STH16(part + (((size_t)(q0<<cshift) + ch)*64 + c)*16, accA);
  STH16(part + (((size_t)(q1<<cshift) + ch)*64 + c)*16, accB);
}

// ---------------- P3q2 ----------------
__global__ __launch_bounds__(256) void pass3_q2(const float4* __restrict__ hatH4,
                                                const float2* __restrict__ rs_g,
                                                const float* __restrict__ v2g,
                                                const float2* __restrict__ aux2,
                                                _Float16* __restrict__ part,
                                                const _Float16* __restrict__ n1h,   // holds n2d
                                                const float* __restrict__ c2f,     // {l1,p2}
                                                int ilen, int nch, int cshift)
{
  WDECODE2();
  float v2A[16], v2B[16];
  LD16(v2A, v2g + ((size_t)q0*64 + c)*16);
  LD16(v2B, v2g + ((size_t)q1*64 + c)*16);
  const float2 a2A = aux2[q0*64+c];
  const float2 a2B = aux2[q1*64+c];
  const float s3A = a2A.x, mv2A = a2A.y;
  const float s3B = a2B.x, mv2B = a2B.y;

  float accA[16], accB[16];
  #pragma unroll
  for (int d=0;d<16;d++){ accA[d]=0.f; accB[d]=0.f; }

  const int i0 = ch*ilen;
  const float4* mp = hatH4 + (size_t)i0*128 + c*2;
  const float2* rp = rs_g + i0*64 + c;
  size_t idxA = ((size_t)q0*512 + i0)*64 + c;
  size_t idxB = idxA + 32768;
  for (int i=0;i<ilen;i++, mp+=128, rp+=64, idxA+=64, idxB+=64){
    half2_t h[8];
    LDH(h, mp);
    float mr[16];
    CVT16(mr, h);
    const float2 rn = *rp;
    float cwA, cwB;
    DOT16(cwA, mr, v2A);
    DOT16(cwB, mr, v2B);
    half2_t cA = __builtin_bit_cast(half2_t, c2f[idxA]);
    half2_t cB = __builtin_bit_cast(half2_t, c2f[idxB]);
    const float l1A = (float)cA.x, p2A = (float)cA.y;
    const float l1B = (float)cB.x, p2B = (float)cB.y;
    const float n2A = (float)n1h[idxA];
    const float n2B = (float)n1h[idxB];
    const float n3A = 0.5f*(n2A + cwA - mv2A*rn.y);
    const float p3A = tanh_pade(n3A*rn.x*s3A);
    const float n3B = 0.5f*(n2B + cwB - mv2B*rn.y);
    const float p3B = tanh_pade(n3B*rn.x*s3B);
    const float eA = __expf(fmaf(p2A, cwA, l1A));
    const float eB = __expf(fmaf(p2B, cwB, l1B));
    const float SA = wave_sum64_all(eA);
    const float SB = wave_sum64_all(eB);
    const float wA = eA*RCP(SA) + p3A;
    const float wB = eB*RCP(SB) + p3B;
    ACCUM(accA, mr, wA);
    ACCUM(accB, mr, wB);
  }
  STH16(part + (((size_t)(q0<<cshift) + ch)*64 + c)*16, accA);
  STH16(part + (((size_t)(q1<<cshift) + ch)*64 + c)*16, accB);
}

// ================= non-cached fallback (1q, proven) =================

template<bool CACHED>
__global__ __launch_bounds__(256) void pass1_kernel(const float4* __restrict__ hatH4,
                                                    const float4* __restrict__ qccH4,
                                                    const float* __restrict__ s1g,
                                                    const float2* __restrict__ rs_g,
                                                    _Float16* __restrict__ part,
                                                    _Float16* __restrict__ n1h,
                                                    int ilen, int nch, int cshift)
{
  WDECODE();
  float qcc1[16];
  {
    half2_t qh[8];
    LDH(qh, qccH4 + (size_t)q*128 + c*2);
    CVT16(qcc1, qh);
  }
  const float s1 = s1g[q*64+c];

  float acc[16];
  #pragma unroll
  for (int d=0;d<16;d++) acc[d]=0.f;

  const int i0 = ch*ilen;
  const float4* mp = hatH4 + (size_t)i0*128 + c*2;
  const float2* rp = rs_g + i0*64 + c;
  size_t idx = ((size_t)q*512 + i0)*64 + c;
  for (int i=0;i<ilen;i+=2, mp+=256, rp+=128, idx+=128){
    half2_t ha[8], hb[8];
    LDH(ha, mp); LDH(hb, mp+128);
    float ma[16], mb[16];
    CVT16(ma, ha); CVT16(mb, hb);
    const float ra = rp[0].x, rb = rp[64].x;
    float nA, nB;
    DOT16(nA, ma, qcc1);
    DOT16(nB, mb, qcc1);
    if (CACHED){
      n1h[idx]    = (_Float16)nA;
      n1h[idx+64] = (_Float16)nB;
    }
    const float wA = 0.015625f + tanh_pade(nA*ra*s1);
    const float wB = 0.015625f + tanh_pade(nB*rb*s1);
    ACCUM(acc, ma, wA);
    ACCUM(acc, mb, wB);
  }
  STH16(part + (((size_t)(q<<cshift) + ch)*64 + c)*16, acc);
}

// ---------------- R1 ----------------
__global__ __launch_bounds__(256) void reduce1_kernel(const float* __restrict__ hat,
                                                      const _Float16* __restrict__ part,
                                                      float* __restrict__ v1g,
                                                      float2* __restrict__ aux1,
                                                      int nchunk)
{
  const int tid = threadIdx.x;
  const int q = blockIdx.x*4 + (tid>>6), c = tid & 63;
  float hv[16];
  #pragma unroll
  for (int d=0;d<16;d++) hv[d]=0.f;
  const _Float16* pp = part + ((size_t)q*nchunk*64 + c)*16;
  for (int ch=0; ch<nchunk; ch++, pp += 1024){
    half2_t th[8]; LDH(th, pp);
    float t[16]; CVT16(t, th);
    #pragma unroll
    for (int d=0;d<16;d++) hv[d]+=t[d];
  }
  float n2=0.f;
  #pragma unroll
  for (int d=0;d<16;d++) n2 += hv[d]*hv[d];
  const float sc = n2 / ((1.0f+n2)*sqrtf(n2+1e-8f));
  float v1[16]; float sv=0.f;
  #pragma unroll
  for (int d=0;d<16;d++){ v1[d]=hv[d]*sc; sv+=v1[d]; }
  ST16(v1g + ((size_t)q*64 + c)*16, v1);
  float qc[16]; LD16(qc, hat + (size_t)(IN_CAPS+q)*CD + c*16);
  float s=0.f, ss=0.f;
  #pragma unroll
  for (int d=0;d<16;d++){ const float t2 = 0.5f*(qc[d]+v1[d]); s+=t2; ss+=t2*t2; }
  const float mean = s*(1.0f/16.0f);
  aux1[q*64+c] = make_float2(__frsqrt_rn(ss - 16.0f*mean*mean + 1e-12f), sv*(1.0f/16.0f));
}

template<bool CACHED>
__global__ __launch_bounds__(256) void pass2_kernel(const float4* __restrict__ hatH4,
                                                    const float* __restrict__ hat,
                                                    const float2* __restrict__ rs_g,
                                                    const float* __restrict__ s1g,
                                                    const float* __restrict__ v1g,
                                                    const float2* __restrict__ aux1,
                                                    _Float16* __restrict__ part,
                                                    _Float16* __restrict__ n1h,
                                                    float* __restrict__ c2f,
                                                    int ilen, int nch, int cshift)
{
  WDECODE();
  float qcc1[16]; float s1;
  if (CACHED){
    s1 = s1g[q*64+c];
  } else {
    QSTAT(qcc1, s1, q);
  }
  float v1[16];
  LD16(v1, v1g + ((size_t)q*64 + c)*16);
  const float2 a1 = aux1[q*64+c];
  const float s2 = a1.x, mv1 = a1.y;

  float acc[16];
  #pragma unroll
  for (int d=0;d<16;d++) acc[d]=0.f;

  const int i0 = ch*ilen;
  const float4* mp = hatH4 + (size_t)i0*128 + c*2;
  const float2* rp = rs_g + i0*64 + c;
  size_t idx = ((size_t)q*512 + i0)*64 + c;
  for (int i=0;i<ilen;i+=2, mp+=256, rp+=128, idx+=128){
    half2_t ha[8], hb[8];
    LDH(ha, mp); LDH(hb, mp+128);
    float ma[16], mb[16];
    CVT16(ma, ha); CVT16(mb, hb);
    const float2 ra = rp[0], rb = rp[64];
    float n1A, n1B, cvA, cvB;
    if (CACHED){
      n1A = (float)n1h[idx];
      n1B = (float)n1h[idx+64];
    } else {
      DOT16(n1A, ma, qcc1);
      DOT16(n1B, mb, qcc1);
    }
    DOT16(cvA, ma, v1);
    DOT16(cvB, mb, v1);
    const float p1A = tanh_pade(n1A*ra.x*s1);
    const float n2A = 0.5f*(n1A + cvA - mv1*ra.y);
    const float p2A = tanh_pade(n2A*ra.x*s2);
    const float p1B = tanh_pade(n1B*rb.x*s1);
    const float n2B = 0.5f*(n1B + cvB - mv1*rb.y);
    const float p2B = tanh_pade(n2B*rb.x*s2);
    const float l1A = p1A*cvA;
    const float l1B = p1B*cvB;
    if (CACHED){
      half2_t cA; cA.x = (_Float16)l1A; cA.y = (_Float16)p2A;
      half2_t cB; cB.x = (_Float16)l1B; cB.y = (_Float16)p2B;
      c2f[idx]    = __builtin_bit_cast(float, cA);
      c2f[idx+64] = __builtin_bit_cast(float, cB);
      n1h[idx]    = (_Float16)n2A;
      n1h[idx+64] = (_Float16)n2B;
    }
    const float eA = __expf(l1A);
    const float eB = __expf(l1B);
    const float SA = wave_sum64_all(eA);
    const float SB = wave_sum64_all(eB);
    const float wA = eA*RCP(SA) + p2A;
    const float wB = eB*RCP(SB) + p2B;
    ACCUM(acc, ma, wA);
    ACCUM(acc, mb, wB);
  }
  STH16(part + (((size_t)(q<<cshift) + ch)*64 + c)*16, acc);
}

// ---------------- R2 ----------------
__global__ __launch_bounds__(256) void reduce2_kernel(const float* __restrict__ hat,
                                                      const _Float16* __restrict__ part,
                                                      const float* __restrict__ v1g,
                                                      float* __restrict__ v2g,
                                                      float2* __restrict__ aux2,
                                                      int nchunk)
{
  const int tid = threadIdx.x;
  const int q = blockIdx.x*4 + (tid>>6), c = tid & 63;
  float hv[16];
  #pragma unroll
  for (int d=0;d<16;d++) hv[d]=0.f;
  const _Float16* pp = part + ((size_t)q*nchunk*64 + c)*16;
  for (int ch=0; ch<nchunk; ch++, pp += 1024){
    half2_t th[8]; LDH(th, pp);
    float t[16]; CVT16(t, th);
    #pragma unroll
    for (int d=0;d<16;d++) hv[d]+=t[d];
  }
  float n2=0.f;
  #pragma unroll
  for (int d=0;d<16;d++) n2 += hv[d]*hv[d];
  const float sc = n2 / ((1.0f+n2)*sqrtf(n2+1e-8f));
  float v2[16]; float sv=0.f;
  #pragma unroll
  for (int d=0;d<16;d++){ v2[d]=hv[d]*sc; sv+=v2[d]; }
  ST16(v2g + ((size_t)q*64 + c)*16, v2);
  float qc[16];  LD16(qc, hat + (size_t)(IN_CAPS+q)*CD + c*16);
  float v1[16];  LD16(v1, v1g + ((size_t)q*64 + c)*16);
  float s=0.f, ss=0.f;
  #pragma unroll
  for (int d=0;d<16;d++){
    const float t3 = 0.25f*qc[d] + 0.25f*v1[d] + 0.5f*v2[d];   // q_cur3
    s+=t3; ss+=t3*t3;
  }
  const float mean = s*(1.0f/16.0f);
  aux2[q*64+c] = make_float2(__frsqrt_rn(ss - 16.0f*mean*mean + 1e-12f), sv*(1.0f/16.0f));
}

template<bool CACHED>
__global__ __launch_bounds__(256) void pass3_kernel(const float4* __restrict__ hatH4,
                                                    const float* __restrict__ hat,
                                                    const float2* __restrict__ rs_g,
                                                    const float* __restrict__ v1g,
                                                    const float* __restrict__ v2g,
                                                    const float2* __restrict__ aux1,
                                                    const float2* __restrict__ aux2,
                                                    _Float16* __restrict__ part,
                                                    const _Float16* __restrict__ n1h,
                                                    const float* __restrict__ c2f,
                                                    int ilen, int nch, int cshift)
{
  WDECODE();
  float v2[16];
  LD16(v2, v2g + ((size_t)q*64 + c)*16);
  const float2 a2 = aux2[q*64+c];
  const float s3 = a2.x, mv2 = a2.y;

  float qcc1[16]; float s1=0.f, s2=0.f, mv1=0.f;
  float v1[16];
  if (!CACHED){
    QSTAT(qcc1, s1, q);
    LD16(v1, v1g + ((size_t)q*64 + c)*16);
    const float2 a1 = aux1[q*64+c];
    s2 = a1.x; mv1 = a1.y;
  }

  float acc[16];
  #pragma unroll
  for (int d=0;d<16;d++) acc[d]=0.f;

  const int i0 = ch*ilen;
  const float4* mp = hatH4 + (size_t)i0*128 + c*2;
  const float2* rp = rs_g + i0*64 + c;
  size_t idx = ((size_t)q*512 + i0)*64 + c;
  for (int i=0;i<ilen;i+=2, mp+=256, rp+=128, idx+=128){
    half2_t ha[8], hb[8];
    LDH(ha, mp); LDH(hb, mp+128);
    float ma[16], mb[16];
    CVT16(ma, ha); CVT16(mb, hb);
    const float2 ra = rp[0], rb = rp[64];
    float cwA, cwB;
    DOT16(cwA, ma, v2);
    DOT16(cwB, mb, v2);
    float l1A, p2A, n2A, l1B, p2B, n2B;
    if (CACHED){
      half2_t cA = __builtin_bit_cast(half2_t, c2f[idx]);
      half2_t cB = __builtin_bit_cast(half2_t, c2f[idx+64]);
      l1A = (float)cA.x; p2A = (float)cA.y;
      l1B = (float)cB.x; p2B = (float)cB.y;
      n2A = (float)n1h[idx];
      n2B = (float)n1h[idx+64];
    } else {
      float n1A, cvA, n1B, cvB;
      DOT16(n1A, ma, qcc1); DOT16(cvA, ma, v1);
      DOT16(n1B, mb, qcc1); DOT16(cvB, mb, v1);
      const float p1A = tanh_pade(n1A*ra.x*s1);
      n2A = 0.5f*(n1A + cvA - mv1*ra.y);
      p2A = tanh_pade(n2A*ra.x*s2);
      l1A = p1A*cvA;
      const float p1B = tanh_pade(n1B*rb.x*s1);
      n2B = 0.5f*(n1B + cvB - mv1*rb.y);
      p2B = tanh_pade(n2B*rb.x*s2);
      l1B = p1B*cvB;
    }
    const float n3A = 0.5f*(n2A + cwA - mv2*ra.y);
    const float p3A = tanh_pade(n3A*ra.x*s3);
    const float n3B = 0.5f*(n2B + cwB - mv2*rb.y);
    const float p3B = tanh_pade(n3B*rb.x*s3);
    const float eA = __expf(fmaf(p2A, cwA, l1A));
    const float eB = __expf(fmaf(p2B, cwB, l1B));
    const float SA = wave_sum64_all(eA);
    const float SB = wave_sum64_all(eB);
    const float wA = eA*RCP(SA) + p3A;
    const float wB = eB*RCP(SB) + p3B;
    ACCUM(acc, ma, wA);
    ACCUM(acc, mb, wB);
  }
  STH16(part + (((size_t)(q<<cshift) + ch)*64 + c)*16, acc);
}

// ---------------- R3 ----------------
__global__ __launch_bounds__(256) void reduce3_kernel(const _Float16* __restrict__ part,
                                                      float* __restrict__ out,
                                                      int nchunk)
{
  const int tid = threadIdx.x;
  const int q = blockIdx.x*4 + (tid>>6), c = tid & 63;
  float hv[16];
  #pragma unroll
  for (int d=0;d<16;d++) hv[d]=0.f;
  const _Float16* pp = part + ((size_t)q*nchunk*64 + c)*16;
  for (int ch=0; ch<nchunk; ch++, pp += 1024){
    half2_t th[8]; LDH(th, pp);
    float t[16]; CVT16(t, th);
    #pragma unroll
    for (int d=0;d<16;d++) hv[d]+=t[d];
  }
  float n2=0.f;
  #pragma unroll
  for (int d=0;d<16;d++) n2 += hv[d]*hv[d];
  const float sc = n2 / ((1.0f+n2)*sqrtf(n2+1e-8f));
  float o[16];
  #pragma unroll
  for (int d=0;d<16;d++) o[d] = hv[d]*sc;
  ST16(out + (size_t)q*CD + c*16, o);
}

extern "C" void kernel_launch(void* const* d_in, const int* in_sizes, int n_in,
                              void* d_out, int out_size, void* d_ws, size_t ws_size,
                              hipStream_t stream)
{
  const float* m  = (const float*)d_in[0];
  const float* q  = (const float*)d_in[1];
  const float* Ww = (const float*)d_in[2];
  const float* Wb = (const float*)d_in[3];
  float* out = (float*)d_out;

  char* ws = (char*)d_ws;
  float*    hat  = (float*)   (ws + 0);
  float2*   rs   = (float2*)  (ws + 4194304);
  _Float16* hatH = (_Float16*)(ws + 4456448);
  float*    s1g  = (float*)   (ws + 5505024);
  _Float16* qccH = (_Float16*)(ws + 5636096);
  float*    v1g  = (float*)   (ws + 6684672);
  float*    v2g  = (float*)   (ws + 8781824);
  float2*   aux1 = (float2*)  (ws + 10878976);
  float2*   aux2 = (float2*)  (ws + 11141120);
  const size_t base = 11403264ull;
  const size_t CACHE_BYTES = 33554432ull + 67108864ull;   // n1h + c2f

  auto spanOf = [](int nc){ size_t s = (size_t)nc*1048576ull; return s < 16777216ull ? 16777216ull : s; };

  int nchunk = 16, cshift = 4;
  bool cached;
  {
    int nc = 16, cs = 4;
    while (nc > 1 && base + spanOf(nc) + CACHE_BYTES > ws_size){ nc >>= 1; cs--; }
    cached = (base + spanOf(nc) + CACHE_BYTES <= ws_size);
    if (cached){ nchunk = nc; cshift = cs; }
    else {
      while (nchunk > 1 && base + spanOf(nchunk) > ws_size){ nchunk >>= 1; cshift--; }
    }
  }
  const size_t span = spanOf(nchunk);
  _Float16* part = (_Float16*)(ws + base);
  float*    hatP = (float*)   (ws + base);     // alias (dead before pass1)
  _Float16* n1h  = (_Float16*)(ws + base + span);
  float*    c2f  = (float*)   (ws + base + span + 33554432ull);

  const int ilen = 512 / nchunk;
  const int pblocks  = (QN*nchunk)/4;     // 1q kernels
  const int pblocks2 = (QN/2*nchunk)/4;   // 2q kernels

  dim3 g0(16,16,4);
  gemm_hat<<<g0, 256, 0, stream>>>(m, q, Ww, hatP);
  finish_stats_kernel<<<1024, 256, 0, stream>>>((const float4*)hatP, Wb, (float4*)hat, hatH, rs, s1g, qccH);
  if (cached){
    pass1_q2<<<pblocks2, 256, 0, stream>>>((const float4*)hatH, (const float4*)qccH, s1g, rs, part, n1h, ilen, nchunk, cshift);
    reduce1_kernel<<<128, 256, 0, stream>>>(hat, part, v1g, aux1, nchunk);
    pass2_q2<<<pblocks2, 256, 0, stream>>>((const float4*)hatH, rs, s1g, v1g, aux1, part, n1h, c2f, ilen, nchunk, cshift);
    reduce2_kernel<<<128, 256, 0, stream>>>(hat, part, v1g, v2g, aux2, nchunk);
    pass3_q2<<<pblocks2, 256, 0, stream>>>((const float4*)hatH, rs, v2g, aux2, part, n1h, c2f, ilen, nchunk, cshift);
    reduce3_kernel<<<128, 256, 0, stream>>>(part, out, nchunk);
  } else {
    pass1_kernel<false><<<pblocks, 256, 0, stream>>>((const float4*)hatH, (const float4*)qccH, s1g, rs, part, n1h, ilen, nchunk, cshift);
    reduce1_kernel<<<128, 256, 0, stream>>>(hat, part, v1g, aux1, nchunk);
    pass2_kernel<false><<<pblocks, 256, 0, stream>>>((const float4*)hatH, hat, rs, s1g, v1g, aux1, part, n1h, c2f, ilen, nchunk, cshift);
    reduce2_kernel<<<128, 256, 0, stream>>>(hat, part, v1g, v2g, aux2, nchunk);
    pass3_kernel<false><<<pblocks, 256, 0, stream>>>((const float4*)hatH, hat, rs, v1g, v2g, aux1, aux2, part, n1h, c2f, ilen, nchunk, cshift);
    reduce3_kernel<<<128, 256, 0, stream>>>(part, out, nchunk);
  }
}